// Round 1
// baseline (4717.952 us; speedup 1.0000x reference)
//
#include <hip/hip_runtime.h>
#include <math.h>

// Problem constants (fixed by the reference)
#define BB 4
#define SS 512
#define DM 512
#define HN 8
#define DK 64
#define LN_LAYERS 6
#define DFF 2048
#define MROWS (BB * SS)   // 2048

// ---------------------------------------------------------------------------
// Embedding: h[b,s,:] = emb[x[b,s]] + pe[s,:]
// ---------------------------------------------------------------------------
__global__ void embed_kernel(const int* __restrict__ x, const float* __restrict__ emb,
                             const float* __restrict__ pe, float* __restrict__ h) {
    int idx = blockIdx.x * blockDim.x + threadIdx.x;   // over B*S*D
    int d = idx & (DM - 1);
    int bs = idx / DM;
    int s = bs & (SS - 1);
    int tok = x[bs];
    h[idx] = emb[(size_t)tok * DM + d] + pe[s * DM + d];
}

// ---------------------------------------------------------------------------
// Tiled fp32 GEMM: C[M,N] = A[M,K] @ B[K,N] + bias, with epilogue
//   EPI 0: none; EPI 1: GELU(tanh approx); EPI 2: + R[row,col] (residual)
// 64x64 tile, BK=16, 256 threads, 4x4 microtile.
// ---------------------------------------------------------------------------
template <int EPI>
__global__ void gemm_kernel(const float* __restrict__ A, const float* __restrict__ Bm,
                            const float* __restrict__ bias, const float* __restrict__ R,
                            float* __restrict__ C, int M, int N, int K) {
    __shared__ float As[16][65];   // [k][m], padded
    __shared__ float Bs[16][64];   // [k][n]
    const int tid = threadIdx.x;
    const int tx = tid & 15;       // n-dir
    const int ty = tid >> 4;       // m-dir
    const int m0 = blockIdx.y * 64;
    const int n0 = blockIdx.x * 64;

    float acc[4][4] = {};

    for (int k0 = 0; k0 < K; k0 += 16) {
        // Load A tile (64x16): thread loads 4 consecutive k at one m
        {
            int m = tid >> 2;                 // 0..63
            int kk = (tid & 3) * 4;           // 0,4,8,12
            const float* ap = A + (size_t)(m0 + m) * K + k0 + kk;
            float4 a4 = *reinterpret_cast<const float4*>(ap);
            As[kk + 0][m] = a4.x;
            As[kk + 1][m] = a4.y;
            As[kk + 2][m] = a4.z;
            As[kk + 3][m] = a4.w;
        }
        // Load B tile (16x64): thread loads 4 consecutive n at one k
        {
            int kk = tid >> 4;                // 0..15
            int n = (tid & 15) * 4;           // 0..60
            const float* bp = Bm + (size_t)(k0 + kk) * N + n0 + n;
            *reinterpret_cast<float4*>(&Bs[kk][n]) = *reinterpret_cast<const float4*>(bp);
        }
        __syncthreads();

        #pragma unroll
        for (int kk = 0; kk < 16; kk++) {
            float a[4], b[4];
            #pragma unroll
            for (int i = 0; i < 4; i++) a[i] = As[kk][ty * 4 + i];
            #pragma unroll
            for (int j = 0; j < 4; j++) b[j] = Bs[kk][tx * 4 + j];
            #pragma unroll
            for (int i = 0; i < 4; i++)
                #pragma unroll
                for (int j = 0; j < 4; j++)
                    acc[i][j] += a[i] * b[j];
        }
        __syncthreads();
    }

    #pragma unroll
    for (int i = 0; i < 4; i++) {
        int row = m0 + ty * 4 + i;
        #pragma unroll
        for (int j = 0; j < 4; j++) {
            int col = n0 + tx * 4 + j;
            float v = acc[i][j] + bias[col];
            if (EPI == 1) {
                float t = v + 0.044715f * v * v * v;
                v = 0.5f * v * (1.0f + tanhf(0.7978845608028654f * t));
            } else if (EPI == 2) {
                v += R[(size_t)row * N + col];
            }
            C[(size_t)row * N + col] = v;
        }
    }
}

// ---------------------------------------------------------------------------
// Attention: one block = 4 waves = 4 query rows of one (b, head).
// Computes scores (with key-padding mask from x==0), softmax, writes attn to
// d_out, and computes ctx = attn @ V.
// ---------------------------------------------------------------------------
__global__ void attn_kernel(const float* __restrict__ qb, const float* __restrict__ kb,
                            const float* __restrict__ vb, const int* __restrict__ x,
                            float* __restrict__ attn_out /* base of attns */,
                            float* __restrict__ ctx, int layer) {
    const int id = blockIdx.x;                 // B * H * (S/4) blocks
    const int q4 = id & (SS / 4 - 1);          // 0..127
    const int hh = (id / (SS / 4)) & (HN - 1);
    const int b  = id / ((SS / 4) * HN);
    const int wave = threadIdx.x >> 6;
    const int lane = threadIdx.x & 63;
    const int q = q4 * 4 + wave;

    __shared__ float qs[4][64];
    __shared__ float ps[4][512];

    qs[wave][lane] = qb[(size_t)(b * SS + q) * (HN * DK) + hh * DK + lane];
    __syncthreads();

    const float scale = 0.125f;  // 1/sqrt(64)
    float sc[8];
    #pragma unroll
    for (int j = 0; j < 8; j++) {
        int k = j * 64 + lane;
        const float* krow = kb + (size_t)(b * SS + k) * (HN * DK) + hh * DK;
        float acc = 0.0f;
        #pragma unroll
        for (int d = 0; d < 64; d++) acc += qs[wave][d] * krow[d];
        acc *= scale;
        if (x[b * SS + k] == 0) acc = -1e9f;
        sc[j] = acc;
    }

    // wave-wide max
    float m = sc[0];
    #pragma unroll
    for (int j = 1; j < 8; j++) m = fmaxf(m, sc[j]);
    #pragma unroll
    for (int off = 32; off; off >>= 1) m = fmaxf(m, __shfl_xor(m, off));

    float sum = 0.0f;
    #pragma unroll
    for (int j = 0; j < 8; j++) { sc[j] = expf(sc[j] - m); sum += sc[j]; }
    #pragma unroll
    for (int off = 32; off; off >>= 1) sum += __shfl_xor(sum, off);
    float inv = 1.0f / sum;

    // write attn row + stash in LDS
    size_t arow = ((size_t)((b * LN_LAYERS + layer) * HN + hh) * SS + q) * SS;
    #pragma unroll
    for (int j = 0; j < 8; j++) {
        float p = sc[j] * inv;
        ps[wave][j * 64 + lane] = p;
        attn_out[arow + j * 64 + lane] = p;
    }
    __syncthreads();

    // ctx[q, d=lane] = sum_k p[k] * V[k, d]
    float acc = 0.0f;
    const float* vcol = vb + (size_t)(b * SS) * (HN * DK) + hh * DK + lane;
    for (int k = 0; k < SS; k++)
        acc += ps[wave][k] * vcol[(size_t)k * (HN * DK)];
    ctx[(size_t)(b * SS + q) * (HN * DK) + hh * DK + lane] = acc;
}

// ---------------------------------------------------------------------------
// LayerNorm over D=512: one block (256 threads) per row.
// ---------------------------------------------------------------------------
__global__ void ln_kernel(const float* __restrict__ in, const float* __restrict__ g,
                          const float* __restrict__ bb, float* __restrict__ out) {
    const int row = blockIdx.x;
    const int tid = threadIdx.x;
    const float* r = in + (size_t)row * DM;
    float v0 = r[tid], v1 = r[tid + 256];

    __shared__ float red[4];
    float t = v0 + v1;
    #pragma unroll
    for (int off = 32; off; off >>= 1) t += __shfl_xor(t, off);
    if ((tid & 63) == 0) red[tid >> 6] = t;
    __syncthreads();
    float mean = (red[0] + red[1] + red[2] + red[3]) * (1.0f / 512.0f);

    float d0 = v0 - mean, d1 = v1 - mean;
    float t2 = d0 * d0 + d1 * d1;
    #pragma unroll
    for (int off = 32; off; off >>= 1) t2 += __shfl_xor(t2, off);
    __syncthreads();
    if ((tid & 63) == 0) red[tid >> 6] = t2;
    __syncthreads();
    float var = (red[0] + red[1] + red[2] + red[3]) * (1.0f / 512.0f);
    float rs = 1.0f / sqrtf(var + 1e-5f);

    out[(size_t)row * DM + tid]       = d0 * rs * g[tid] + bb[tid];
    out[(size_t)row * DM + tid + 256] = d1 * rs * g[tid + 256] + bb[tid + 256];
}

// ---------------------------------------------------------------------------
extern "C" void kernel_launch(void* const* d_in, const int* in_sizes, int n_in,
                              void* d_out, int out_size, void* d_ws, size_t ws_size,
                              hipStream_t stream) {
    const int*   x    = (const int*)d_in[0];
    const float* emb  = (const float*)d_in[1];
    const float* pe   = (const float*)d_in[2];
    const float* WQ   = (const float*)d_in[3];
    const float* bQ   = (const float*)d_in[4];
    const float* WK   = (const float*)d_in[5];
    const float* bK   = (const float*)d_in[6];
    const float* WV   = (const float*)d_in[7];
    const float* bV   = (const float*)d_in[8];
    const float* WO   = (const float*)d_in[9];
    const float* bO   = (const float*)d_in[10];
    const float* ln1g = (const float*)d_in[11];
    const float* ln1b = (const float*)d_in[12];
    const float* W1   = (const float*)d_in[13];
    const float* b1   = (const float*)d_in[14];
    const float* W2   = (const float*)d_in[15];
    const float* b2   = (const float*)d_in[16];
    const float* ln2g = (const float*)d_in[17];
    const float* ln2b = (const float*)d_in[18];

    float* out = (float*)d_out;
    const size_t HSIZE = (size_t)MROWS * DM;         // 2048*512 = 1,048,576
    float* attn_base = out + HSIZE;

    // workspace layout (floats)
    float* ws  = (float*)d_ws;
    float* h   = ws;                  // [2048,512]
    float* tmp = h   + HSIZE;         // [2048,512]
    float* qb  = tmp + HSIZE;         // [2048,512]
    float* kb  = qb  + HSIZE;         // [2048,512]
    float* vb  = kb  + HSIZE;         // [2048,512]
    float* ctx = vb  + HSIZE;         // [2048,512]
    float* ff  = ctx + HSIZE;         // [2048,2048]

    embed_kernel<<<(MROWS * DM) / 256, 256, 0, stream>>>(x, emb, pe, h);

    dim3 gD(DM / 64, MROWS / 64);     // N=512 GEMMs
    dim3 gF(DFF / 64, MROWS / 64);    // N=2048 GEMM

    for (int i = 0; i < LN_LAYERS; i++) {
        const float* wq = WQ + (size_t)i * DM * (HN * DK);
        const float* wk = WK + (size_t)i * DM * (HN * DK);
        const float* wv = WV + (size_t)i * DM * (HN * DK);
        const float* wo = WO + (size_t)i * (HN * DK) * DM;

        gemm_kernel<0><<<gD, 256, 0, stream>>>(h, wq, bQ + i * (HN * DK), nullptr, qb, MROWS, HN * DK, DM);
        gemm_kernel<0><<<gD, 256, 0, stream>>>(h, wk, bK + i * (HN * DK), nullptr, kb, MROWS, HN * DK, DM);
        gemm_kernel<0><<<gD, 256, 0, stream>>>(h, wv, bV + i * (HN * DK), nullptr, vb, MROWS, HN * DK, DM);

        attn_kernel<<<BB * HN * (SS / 4), 256, 0, stream>>>(qb, kb, vb, x, attn_base, ctx, i);

        gemm_kernel<2><<<gD, 256, 0, stream>>>(ctx, wo, bO + i * DM, h, tmp, MROWS, DM, HN * DK);
        ln_kernel<<<MROWS, 256, 0, stream>>>(tmp, ln1g + i * DM, ln1b + i * DM, h);

        gemm_kernel<1><<<gF, 256, 0, stream>>>(h, W1 + (size_t)i * DM * DFF, b1 + i * DFF, nullptr, ff, MROWS, DFF, DM);
        gemm_kernel<2><<<gD, 256, 0, stream>>>(ff, W2 + (size_t)i * DFF * DM, b2 + i * DM, h, tmp, MROWS, DM, DFF);
        ln_kernel<<<MROWS, 256, 0, stream>>>(tmp, ln2g + i * DM, ln2b + i * DM, h);
    }

    hipMemcpyAsync(out, h, HSIZE * sizeof(float), hipMemcpyDeviceToDevice, stream);
}

// Round 2
// 2841.123 us; speedup vs baseline: 1.6606x; 1.6606x over previous
//
#include <hip/hip_runtime.h>
#include <math.h>

// Problem constants (fixed by the reference)
#define BB 4
#define SS 512
#define DM 512
#define HN 8
#define DK 64
#define LN_LAYERS 6
#define DFF 2048
#define MROWS (BB * SS)   // 2048

// ---------------------------------------------------------------------------
// Embedding: h[b,s,:] = emb[x[b,s]] + pe[s,:]
// ---------------------------------------------------------------------------
__global__ void embed_kernel(const int* __restrict__ x, const float* __restrict__ emb,
                             const float* __restrict__ pe, float* __restrict__ h) {
    int idx = blockIdx.x * blockDim.x + threadIdx.x;   // over B*S*D
    int d = idx & (DM - 1);
    int bs = idx / DM;
    int s = bs & (SS - 1);
    int tok = x[bs];
    h[idx] = emb[(size_t)tok * DM + d] + pe[s * DM + d];
}

// ---------------------------------------------------------------------------
// Tiled fp32 GEMM: C[M,N] = A[M,K] @ B[K,N] + bias, with epilogue
//   EPI 0: none; EPI 1: GELU(tanh approx); EPI 2: + R[row,col] (residual)
// 64x64 tile, BK=16, 256 threads, 4x4 microtile.
// ---------------------------------------------------------------------------
template <int EPI>
__global__ void gemm_kernel(const float* __restrict__ A, const float* __restrict__ Bm,
                            const float* __restrict__ bias, const float* __restrict__ R,
                            float* __restrict__ C, int M, int N, int K) {
    __shared__ float As[16][65];   // [k][m], padded
    __shared__ float Bs[16][64];   // [k][n]
    const int tid = threadIdx.x;
    const int tx = tid & 15;       // n-dir
    const int ty = tid >> 4;       // m-dir
    const int m0 = blockIdx.y * 64;
    const int n0 = blockIdx.x * 64;

    float acc[4][4] = {};

    for (int k0 = 0; k0 < K; k0 += 16) {
        // Load A tile (64x16): thread loads 4 consecutive k at one m
        {
            int m = tid >> 2;                 // 0..63
            int kk = (tid & 3) * 4;           // 0,4,8,12
            const float* ap = A + (size_t)(m0 + m) * K + k0 + kk;
            float4 a4 = *reinterpret_cast<const float4*>(ap);
            As[kk + 0][m] = a4.x;
            As[kk + 1][m] = a4.y;
            As[kk + 2][m] = a4.z;
            As[kk + 3][m] = a4.w;
        }
        // Load B tile (16x64): thread loads 4 consecutive n at one k
        {
            int kk = tid >> 4;                // 0..15
            int n = (tid & 15) * 4;           // 0..60
            const float* bp = Bm + (size_t)(k0 + kk) * N + n0 + n;
            *reinterpret_cast<float4*>(&Bs[kk][n]) = *reinterpret_cast<const float4*>(bp);
        }
        __syncthreads();

        #pragma unroll
        for (int kk = 0; kk < 16; kk++) {
            float a[4], b[4];
            #pragma unroll
            for (int i = 0; i < 4; i++) a[i] = As[kk][ty * 4 + i];
            #pragma unroll
            for (int j = 0; j < 4; j++) b[j] = Bs[kk][tx * 4 + j];
            #pragma unroll
            for (int i = 0; i < 4; i++)
                #pragma unroll
                for (int j = 0; j < 4; j++)
                    acc[i][j] += a[i] * b[j];
        }
        __syncthreads();
    }

    #pragma unroll
    for (int i = 0; i < 4; i++) {
        int row = m0 + ty * 4 + i;
        #pragma unroll
        for (int j = 0; j < 4; j++) {
            int col = n0 + tx * 4 + j;
            float v = acc[i][j] + bias[col];
            if (EPI == 1) {
                float t = v + 0.044715f * v * v * v;
                v = 0.5f * v * (1.0f + tanhf(0.7978845608028654f * t));
            } else if (EPI == 2) {
                v += R[(size_t)row * N + col];
            }
            C[(size_t)row * N + col] = v;
        }
    }
}

// ---------------------------------------------------------------------------
// Attention v2: tiled two-pass flash-style.
// Block = 256 threads, handles one (b, head, 64-query tile). Grid = 4*8*8 = 256.
// Pass 1: online (max,sum) per row over LDS-staged transposed K tiles.
// Pass 2: recompute scores, normalize, write attn (coalesced float4), PV via
// LDS-staged P and V. Stride-68 LDS rows keep b128 reads aligned and <=2-way
// bank conflicts (free).
// ---------------------------------------------------------------------------
__global__ __launch_bounds__(256) void attn_kernel(
        const float* __restrict__ qb, const float* __restrict__ kb,
        const float* __restrict__ vb, const int* __restrict__ x,
        float* __restrict__ attn_out, float* __restrict__ ctx, int layer) {
    const int bid = blockIdx.x;
    const int qt = bid & 7;              // query tile (0..7)
    const int hh = (bid >> 3) & 7;       // head
    const int b  = bid >> 6;             // batch
    const int tid = threadIdx.x;
    const int tx = tid & 15;             // k / d direction (4 each)
    const int ty = tid >> 4;             // q direction (4 each)
    const int q0 = qt * 64;

    __shared__ float Qt[64][68];   // [d][q]  (transposed)
    __shared__ float Kt[64][68];   // [d][k]  (transposed)
    __shared__ float Vs[64][68];   // [k][d]  (natural)
    __shared__ float Ps[64][68];   // [q][k]
    __shared__ float madd[SS];     // additive key mask

    // mask staging
    madd[tid]       = (x[b * SS + tid] == 0)       ? -1e9f : 0.0f;
    madd[tid + 256] = (x[b * SS + tid + 256] == 0) ? -1e9f : 0.0f;

    // Q tile staged transposed: thread loads row q=tid>>2, 16 d-cols
    {
        int r = tid >> 2;
        int c0 = (tid & 3) * 16;
        const float* gp = qb + (size_t)(b * SS + q0 + r) * (HN * DK) + hh * DK + c0;
        #pragma unroll
        for (int c = 0; c < 16; c += 4) {
            float4 v4 = *reinterpret_cast<const float4*>(gp + c);
            Qt[c0 + c + 0][r] = v4.x;
            Qt[c0 + c + 1][r] = v4.y;
            Qt[c0 + c + 2][r] = v4.z;
            Qt[c0 + c + 3][r] = v4.w;
        }
    }
    __syncthreads();

    const float scale = 0.125f;
    float mrow[4], lrow[4];
    #pragma unroll
    for (int i = 0; i < 4; i++) { mrow[i] = -1e30f; lrow[i] = 0.0f; }

    // ---------------- Pass 1: online (m,l) ----------------
    for (int kt2 = 0; kt2 < 8; kt2++) {
        {   // stage K tile transposed
            int r = tid >> 2;
            int c0 = (tid & 3) * 16;
            const float* gp = kb + (size_t)(b * SS + kt2 * 64 + r) * (HN * DK) + hh * DK + c0;
            #pragma unroll
            for (int c = 0; c < 16; c += 4) {
                float4 v4 = *reinterpret_cast<const float4*>(gp + c);
                Kt[c0 + c + 0][r] = v4.x;
                Kt[c0 + c + 1][r] = v4.y;
                Kt[c0 + c + 2][r] = v4.z;
                Kt[c0 + c + 3][r] = v4.w;
            }
        }
        __syncthreads();

        float s[4][4] = {};
        #pragma unroll 8
        for (int d = 0; d < 64; d++) {
            float4 a4 = *reinterpret_cast<const float4*>(&Qt[d][ty * 4]);
            float4 b4 = *reinterpret_cast<const float4*>(&Kt[d][tx * 4]);
            float a[4] = {a4.x, a4.y, a4.z, a4.w};
            float bq[4] = {b4.x, b4.y, b4.z, b4.w};
            #pragma unroll
            for (int i = 0; i < 4; i++)
                #pragma unroll
                for (int j = 0; j < 4; j++)
                    s[i][j] += a[i] * bq[j];
        }
        #pragma unroll
        for (int i = 0; i < 4; i++) {
            float sv[4], tmax;
            #pragma unroll
            for (int j = 0; j < 4; j++)
                sv[j] = s[i][j] * scale + madd[kt2 * 64 + tx * 4 + j];
            tmax = fmaxf(fmaxf(sv[0], sv[1]), fmaxf(sv[2], sv[3]));
            float nm = fmaxf(mrow[i], tmax);
            float acc = lrow[i] * __expf(mrow[i] - nm);
            #pragma unroll
            for (int j = 0; j < 4; j++) acc += __expf(sv[j] - nm);
            lrow[i] = acc;
            mrow[i] = nm;
        }
        __syncthreads();
    }

    // merge (m,l) across the 16-lane tx group
    #pragma unroll
    for (int off = 1; off < 16; off <<= 1) {
        #pragma unroll
        for (int i = 0; i < 4; i++) {
            float m2 = __shfl_xor(mrow[i], off);
            float l2 = __shfl_xor(lrow[i], off);
            float nm = fmaxf(mrow[i], m2);
            lrow[i] = lrow[i] * __expf(mrow[i] - nm) + l2 * __expf(m2 - nm);
            mrow[i] = nm;
        }
    }
    float inv[4];
    #pragma unroll
    for (int i = 0; i < 4; i++) inv[i] = 1.0f / lrow[i];

    // ---------------- Pass 2: normalize, write attn, PV ----------------
    float cacc[4][4] = {};
    const size_t arow0 = ((size_t)((b * LN_LAYERS + layer) * HN + hh) * SS + (q0 + ty * 4)) * SS;

    for (int kt2 = 0; kt2 < 8; kt2++) {
        {   // stage K tile transposed + V tile natural
            int r = tid >> 2;
            int c0 = (tid & 3) * 16;
            const float* gpk = kb + (size_t)(b * SS + kt2 * 64 + r) * (HN * DK) + hh * DK + c0;
            const float* gpv = vb + (size_t)(b * SS + kt2 * 64 + r) * (HN * DK) + hh * DK + c0;
            #pragma unroll
            for (int c = 0; c < 16; c += 4) {
                float4 v4 = *reinterpret_cast<const float4*>(gpk + c);
                Kt[c0 + c + 0][r] = v4.x;
                Kt[c0 + c + 1][r] = v4.y;
                Kt[c0 + c + 2][r] = v4.z;
                Kt[c0 + c + 3][r] = v4.w;
                *reinterpret_cast<float4*>(&Vs[r][c0 + c]) = *reinterpret_cast<const float4*>(gpv + c);
            }
        }
        __syncthreads();

        float s[4][4] = {};
        #pragma unroll 8
        for (int d = 0; d < 64; d++) {
            float4 a4 = *reinterpret_cast<const float4*>(&Qt[d][ty * 4]);
            float4 b4 = *reinterpret_cast<const float4*>(&Kt[d][tx * 4]);
            float a[4] = {a4.x, a4.y, a4.z, a4.w};
            float bq[4] = {b4.x, b4.y, b4.z, b4.w};
            #pragma unroll
            for (int i = 0; i < 4; i++)
                #pragma unroll
                for (int j = 0; j < 4; j++)
                    s[i][j] += a[i] * bq[j];
        }
        #pragma unroll
        for (int i = 0; i < 4; i++) {
            float4 pv;
            pv.x = __expf(s[i][0] * scale + madd[kt2 * 64 + tx * 4 + 0] - mrow[i]) * inv[i];
            pv.y = __expf(s[i][1] * scale + madd[kt2 * 64 + tx * 4 + 1] - mrow[i]) * inv[i];
            pv.z = __expf(s[i][2] * scale + madd[kt2 * 64 + tx * 4 + 2] - mrow[i]) * inv[i];
            pv.w = __expf(s[i][3] * scale + madd[kt2 * 64 + tx * 4 + 3] - mrow[i]) * inv[i];
            *reinterpret_cast<float4*>(&attn_out[arow0 + (size_t)i * SS + kt2 * 64 + tx * 4]) = pv;
            *reinterpret_cast<float4*>(&Ps[ty * 4 + i][tx * 4]) = pv;
        }
        __syncthreads();

        // PV: ctx[q][d] += P[q][kk] * V[kk][d], 4 kk per step
        #pragma unroll 4
        for (int kk4 = 0; kk4 < 16; kk4++) {
            float4 aq[4], bq[4];
            #pragma unroll
            for (int i = 0; i < 4; i++)
                aq[i] = *reinterpret_cast<const float4*>(&Ps[ty * 4 + i][kk4 * 4]);
            #pragma unroll
            for (int e = 0; e < 4; e++)
                bq[e] = *reinterpret_cast<const float4*>(&Vs[kk4 * 4 + e][tx * 4]);
            #pragma unroll
            for (int i = 0; i < 4; i++) {
                float av[4] = {aq[i].x, aq[i].y, aq[i].z, aq[i].w};
                #pragma unroll
                for (int e = 0; e < 4; e++) {
                    cacc[i][0] += av[e] * bq[e].x;
                    cacc[i][1] += av[e] * bq[e].y;
                    cacc[i][2] += av[e] * bq[e].z;
                    cacc[i][3] += av[e] * bq[e].w;
                }
            }
        }
        __syncthreads();
    }

    #pragma unroll
    for (int i = 0; i < 4; i++) {
        float4 cv = make_float4(cacc[i][0], cacc[i][1], cacc[i][2], cacc[i][3]);
        *reinterpret_cast<float4*>(&ctx[(size_t)(b * SS + q0 + ty * 4 + i) * (HN * DK) + hh * DK + tx * 4]) = cv;
    }
}

// ---------------------------------------------------------------------------
// LayerNorm over D=512: one block (256 threads) per row.
// ---------------------------------------------------------------------------
__global__ void ln_kernel(const float* __restrict__ in, const float* __restrict__ g,
                          const float* __restrict__ bb, float* __restrict__ out) {
    const int row = blockIdx.x;
    const int tid = threadIdx.x;
    const float* r = in + (size_t)row * DM;
    float v0 = r[tid], v1 = r[tid + 256];

    __shared__ float red[4];
    float t = v0 + v1;
    #pragma unroll
    for (int off = 32; off; off >>= 1) t += __shfl_xor(t, off);
    if ((tid & 63) == 0) red[tid >> 6] = t;
    __syncthreads();
    float mean = (red[0] + red[1] + red[2] + red[3]) * (1.0f / 512.0f);

    float d0 = v0 - mean, d1 = v1 - mean;
    float t2 = d0 * d0 + d1 * d1;
    #pragma unroll
    for (int off = 32; off; off >>= 1) t2 += __shfl_xor(t2, off);
    __syncthreads();
    if ((tid & 63) == 0) red[tid >> 6] = t2;
    __syncthreads();
    float var = (red[0] + red[1] + red[2] + red[3]) * (1.0f / 512.0f);
    float rs = 1.0f / sqrtf(var + 1e-5f);

    out[(size_t)row * DM + tid]       = d0 * rs * g[tid] + bb[tid];
    out[(size_t)row * DM + tid + 256] = d1 * rs * g[tid + 256] + bb[tid + 256];
}

// ---------------------------------------------------------------------------
extern "C" void kernel_launch(void* const* d_in, const int* in_sizes, int n_in,
                              void* d_out, int out_size, void* d_ws, size_t ws_size,
                              hipStream_t stream) {
    const int*   x    = (const int*)d_in[0];
    const float* emb  = (const float*)d_in[1];
    const float* pe   = (const float*)d_in[2];
    const float* WQ   = (const float*)d_in[3];
    const float* bQ   = (const float*)d_in[4];
    const float* WK   = (const float*)d_in[5];
    const float* bK   = (const float*)d_in[6];
    const float* WV   = (const float*)d_in[7];
    const float* bV   = (const float*)d_in[8];
    const float* WO   = (const float*)d_in[9];
    const float* bO   = (const float*)d_in[10];
    const float* ln1g = (const float*)d_in[11];
    const float* ln1b = (const float*)d_in[12];
    const float* W1   = (const float*)d_in[13];
    const float* b1   = (const float*)d_in[14];
    const float* W2   = (const float*)d_in[15];
    const float* b2   = (const float*)d_in[16];
    const float* ln2g = (const float*)d_in[17];
    const float* ln2b = (const float*)d_in[18];

    float* out = (float*)d_out;
    const size_t HSIZE = (size_t)MROWS * DM;         // 2048*512 = 1,048,576
    float* attn_base = out + HSIZE;

    // workspace layout (floats)
    float* ws  = (float*)d_ws;
    float* h   = ws;                  // [2048,512]
    float* tmp = h   + HSIZE;         // [2048,512]
    float* qb  = tmp + HSIZE;         // [2048,512]
    float* kb  = qb  + HSIZE;         // [2048,512]
    float* vb  = kb  + HSIZE;         // [2048,512]
    float* ctx = vb  + HSIZE;         // [2048,512]
    float* ff  = ctx + HSIZE;         // [2048,2048]

    embed_kernel<<<(MROWS * DM) / 256, 256, 0, stream>>>(x, emb, pe, h);

    dim3 gD(DM / 64, MROWS / 64);     // N=512 GEMMs
    dim3 gF(DFF / 64, MROWS / 64);    // N=2048 GEMM

    for (int i = 0; i < LN_LAYERS; i++) {
        const float* wq = WQ + (size_t)i * DM * (HN * DK);
        const float* wk = WK + (size_t)i * DM * (HN * DK);
        const float* wv = WV + (size_t)i * DM * (HN * DK);
        const float* wo = WO + (size_t)i * (HN * DK) * DM;

        gemm_kernel<0><<<gD, 256, 0, stream>>>(h, wq, bQ + i * (HN * DK), nullptr, qb, MROWS, HN * DK, DM);
        gemm_kernel<0><<<gD, 256, 0, stream>>>(h, wk, bK + i * (HN * DK), nullptr, kb, MROWS, HN * DK, DM);
        gemm_kernel<0><<<gD, 256, 0, stream>>>(h, wv, bV + i * (HN * DK), nullptr, vb, MROWS, HN * DK, DM);

        attn_kernel<<<BB * HN * (SS / 64), 256, 0, stream>>>(qb, kb, vb, x, attn_base, ctx, i);

        gemm_kernel<2><<<gD, 256, 0, stream>>>(ctx, wo, bO + i * DM, h, tmp, MROWS, DM, HN * DK);
        ln_kernel<<<MROWS, 256, 0, stream>>>(tmp, ln1g + i * DM, ln1b + i * DM, h);

        gemm_kernel<1><<<gF, 256, 0, stream>>>(h, W1 + (size_t)i * DM * DFF, b1 + i * DFF, nullptr, ff, MROWS, DFF, DM);
        gemm_kernel<2><<<gD, 256, 0, stream>>>(ff, W2 + (size_t)i * DFF * DM, b2 + i * DM, h, tmp, MROWS, DM, DFF);
        ln_kernel<<<MROWS, 256, 0, stream>>>(tmp, ln2g + i * DM, ln2b + i * DM, h);
    }

    hipMemcpyAsync(out, h, HSIZE * sizeof(float), hipMemcpyDeviceToDevice, stream);
}

// Round 3
// 1713.801 us; speedup vs baseline: 2.7529x; 1.6578x over previous
//
#include <hip/hip_runtime.h>
#include <math.h>

// Problem constants (fixed by the reference)
#define BB 4
#define SS 512
#define DM 512
#define HN 8
#define DK 64
#define LN_LAYERS 6
#define DFF 2048
#define MROWS 2048

typedef float f32x4 __attribute__((ext_vector_type(4)));
typedef short s16x8 __attribute__((ext_vector_type(8)));
typedef unsigned short u16x8 __attribute__((ext_vector_type(8)));

__device__ inline unsigned short bf16_rtne(float f) {
    unsigned u = __float_as_uint(f);
    unsigned r = u + 0x7FFFu + ((u >> 16) & 1u);
    return (unsigned short)(r >> 16);
}
__device__ inline void split2(float a, unsigned short& hi, unsigned short& lo) {
    unsigned short h = bf16_rtne(a);
    hi = h;
    float fh = __uint_as_float(((unsigned)h) << 16);
    lo = bf16_rtne(a - fh);
}

// ---------------------------------------------------------------------------
// Embedding: h[b,s,:] = emb[x[b,s]] + pe[s,:]
// ---------------------------------------------------------------------------
__global__ void embed_kernel(const int* __restrict__ x, const float* __restrict__ emb,
                             const float* __restrict__ pe, float* __restrict__ h) {
    int idx = blockIdx.x * blockDim.x + threadIdx.x;
    int d = idx & (DM - 1);
    int bs = idx / DM;
    int s = bs & (SS - 1);
    int tok = x[bs];
    h[idx] = emb[(size_t)tok * DM + d] + pe[s * DM + d];
}

// ---------------------------------------------------------------------------
// bf16x3 MFMA GEMM body: C[M,N] = A @ B + bias (+epilogue), fp32-grade accuracy
// via A=Ah+Al, B=Bh+Bl splits (drops only lo*lo ~ 2^-16).
// Block = 128 threads (2 waves), tile 32x64, BK=32.
// A/B fragment k-mapping: k = (lane>>4)*8 + j, row/col = lane&15 — any
// consistent bijection is correct; C/D map col=lane&15, row=(lane>>4)*4+reg.
// ---------------------------------------------------------------------------
template <int EPI>
__device__ inline void gemm3_body(const float* __restrict__ A, const float* __restrict__ Bm,
                                  const float* __restrict__ bias, const float* __restrict__ R,
                                  float* __restrict__ C, int N, int K, int m0, int n0) {
    // stride 40 ushorts = 80B rows: b128 frag reads land 2-way conflicts (free)
    __shared__ unsigned short Ah[32][40], Al[32][40];
    __shared__ unsigned short Bh[64][40], Bl[64][40];
    const int t = threadIdx.x;
    const int am = t >> 2;             // 0..31  (A stage row)
    const int ak = (t & 3) * 8;        // 0,8,16,24
    const int bn = t & 63;             // 0..63  (B stage col)
    const int bk0 = (t >> 6) * 8;      // 0 or 8

    const float* Aptr = A + (size_t)(m0 + am) * K + ak;

    float aReg[8], bReg[16];
    {   // first chunk
        float4 a0 = *reinterpret_cast<const float4*>(Aptr);
        float4 a1 = *reinterpret_cast<const float4*>(Aptr + 4);
        aReg[0]=a0.x; aReg[1]=a0.y; aReg[2]=a0.z; aReg[3]=a0.w;
        aReg[4]=a1.x; aReg[5]=a1.y; aReg[6]=a1.z; aReg[7]=a1.w;
        #pragma unroll
        for (int i = 0; i < 8; i++) bReg[i]     = Bm[(size_t)(bk0 + i) * N + n0 + bn];
        #pragma unroll
        for (int i = 0; i < 8; i++) bReg[8 + i] = Bm[(size_t)(16 + bk0 + i) * N + n0 + bn];
    }

    const int w  = t >> 6;
    const int l  = t & 63;
    const int lr = l & 15;
    const int lg = l >> 4;

    f32x4 acc[4] = {};

    for (int k0 = 0; k0 < K; k0 += 32) {
        __syncthreads();
        {   // convert + write LDS
            u16x8 h8, l8;
            #pragma unroll
            for (int i = 0; i < 8; i++) { unsigned short hh, ll; split2(aReg[i], hh, ll); h8[i]=hh; l8[i]=ll; }
            *reinterpret_cast<u16x8*>(&Ah[am][ak]) = h8;
            *reinterpret_cast<u16x8*>(&Al[am][ak]) = l8;
            #pragma unroll
            for (int i = 0; i < 8; i++) { unsigned short hh, ll; split2(bReg[i], hh, ll); h8[i]=hh; l8[i]=ll; }
            *reinterpret_cast<u16x8*>(&Bh[bn][bk0]) = h8;
            *reinterpret_cast<u16x8*>(&Bl[bn][bk0]) = l8;
            #pragma unroll
            for (int i = 0; i < 8; i++) { unsigned short hh, ll; split2(bReg[8+i], hh, ll); h8[i]=hh; l8[i]=ll; }
            *reinterpret_cast<u16x8*>(&Bh[bn][16 + bk0]) = h8;
            *reinterpret_cast<u16x8*>(&Bl[bn][16 + bk0]) = l8;
        }
        __syncthreads();

        if (k0 + 32 < K) {   // prefetch next chunk (hides HBM under MFMA)
            const float* ap = Aptr + k0 + 32;
            float4 a0 = *reinterpret_cast<const float4*>(ap);
            float4 a1 = *reinterpret_cast<const float4*>(ap + 4);
            aReg[0]=a0.x; aReg[1]=a0.y; aReg[2]=a0.z; aReg[3]=a0.w;
            aReg[4]=a1.x; aReg[5]=a1.y; aReg[6]=a1.z; aReg[7]=a1.w;
            #pragma unroll
            for (int i = 0; i < 8; i++) bReg[i]     = Bm[(size_t)(k0 + 32 + bk0 + i) * N + n0 + bn];
            #pragma unroll
            for (int i = 0; i < 8; i++) bReg[8 + i] = Bm[(size_t)(k0 + 48 + bk0 + i) * N + n0 + bn];
        }

        s16x8 ah = *reinterpret_cast<const s16x8*>(&Ah[w * 16 + lr][lg * 8]);
        s16x8 al = *reinterpret_cast<const s16x8*>(&Al[w * 16 + lr][lg * 8]);
        #pragma unroll
        for (int nf = 0; nf < 4; nf++) {
            s16x8 bh = *reinterpret_cast<const s16x8*>(&Bh[nf * 16 + lr][lg * 8]);
            s16x8 bl = *reinterpret_cast<const s16x8*>(&Bl[nf * 16 + lr][lg * 8]);
            acc[nf] = __builtin_amdgcn_mfma_f32_16x16x32_bf16(ah, bl, acc[nf], 0, 0, 0);
            acc[nf] = __builtin_amdgcn_mfma_f32_16x16x32_bf16(al, bh, acc[nf], 0, 0, 0);
            acc[nf] = __builtin_amdgcn_mfma_f32_16x16x32_bf16(ah, bh, acc[nf], 0, 0, 0);
        }
    }

    #pragma unroll
    for (int nf = 0; nf < 4; nf++) {
        int col = n0 + nf * 16 + lr;
        float bsv = bias[col];
        #pragma unroll
        for (int r = 0; r < 4; r++) {
            int row = m0 + w * 16 + lg * 4 + r;
            float v = acc[nf][r] + bsv;
            if (EPI == 1) {
                float u = v + 0.044715f * v * v * v;
                float z2 = 1.5957691216057308f * u;      // 2 * sqrt(2/pi) * u
                float ax = fabsf(z2);
                float e = __expf(ax);
                float th = 1.0f - 2.0f / (e + 1.0f);
                th = (z2 < 0.0f) ? -th : th;
                v = 0.5f * v * (1.0f + th);
            } else if (EPI == 2) {
                v += R[(size_t)row * N + col];
            }
            C[(size_t)row * N + col] = v;
        }
    }
}

template <int EPI>
__global__ __launch_bounds__(128) void gemm3_kernel(const float* __restrict__ A,
        const float* __restrict__ Bm, const float* __restrict__ bias,
        const float* __restrict__ R, float* __restrict__ C, int N, int K) {
    gemm3_body<EPI>(A, Bm, bias, R, C, N, K, blockIdx.y * 32, blockIdx.x * 64);
}

__global__ __launch_bounds__(128) void gemm3_qkv(const float* __restrict__ A,
        const float* __restrict__ WQ, const float* __restrict__ WK, const float* __restrict__ WV,
        const float* __restrict__ bQ, const float* __restrict__ bK, const float* __restrict__ bV,
        float* __restrict__ qb, float* __restrict__ kb, float* __restrict__ vb, int K) {
    const float* Bm; const float* bias; float* C;
    if (blockIdx.z == 0)      { Bm = WQ; bias = bQ; C = qb; }
    else if (blockIdx.z == 1) { Bm = WK; bias = bK; C = kb; }
    else                      { Bm = WV; bias = bV; C = vb; }
    gemm3_body<0>(A, Bm, bias, nullptr, C, DM, K, blockIdx.y * 32, blockIdx.x * 64);
}

// ---------------------------------------------------------------------------
// Attention: tiled two-pass flash-style (unchanged from round 2).
// ---------------------------------------------------------------------------
__global__ __launch_bounds__(256) void attn_kernel(
        const float* __restrict__ qb, const float* __restrict__ kb,
        const float* __restrict__ vb, const int* __restrict__ x,
        float* __restrict__ attn_out, float* __restrict__ ctx, int layer) {
    const int bid = blockIdx.x;
    const int qt = bid & 7;
    const int hh = (bid >> 3) & 7;
    const int b  = bid >> 6;
    const int tid = threadIdx.x;
    const int tx = tid & 15;
    const int ty = tid >> 4;
    const int q0 = qt * 64;

    __shared__ float Qt[64][68];
    __shared__ float Kt[64][68];
    __shared__ float Vs[64][68];
    __shared__ float Ps[64][68];
    __shared__ float madd[SS];

    madd[tid]       = (x[b * SS + tid] == 0)       ? -1e9f : 0.0f;
    madd[tid + 256] = (x[b * SS + tid + 256] == 0) ? -1e9f : 0.0f;

    {
        int r = tid >> 2;
        int c0 = (tid & 3) * 16;
        const float* gp = qb + (size_t)(b * SS + q0 + r) * (HN * DK) + hh * DK + c0;
        #pragma unroll
        for (int c = 0; c < 16; c += 4) {
            float4 v4 = *reinterpret_cast<const float4*>(gp + c);
            Qt[c0 + c + 0][r] = v4.x;
            Qt[c0 + c + 1][r] = v4.y;
            Qt[c0 + c + 2][r] = v4.z;
            Qt[c0 + c + 3][r] = v4.w;
        }
    }
    __syncthreads();

    const float scale = 0.125f;
    float mrow[4], lrow[4];
    #pragma unroll
    for (int i = 0; i < 4; i++) { mrow[i] = -1e30f; lrow[i] = 0.0f; }

    for (int kt2 = 0; kt2 < 8; kt2++) {
        {
            int r = tid >> 2;
            int c0 = (tid & 3) * 16;
            const float* gp = kb + (size_t)(b * SS + kt2 * 64 + r) * (HN * DK) + hh * DK + c0;
            #pragma unroll
            for (int c = 0; c < 16; c += 4) {
                float4 v4 = *reinterpret_cast<const float4*>(gp + c);
                Kt[c0 + c + 0][r] = v4.x;
                Kt[c0 + c + 1][r] = v4.y;
                Kt[c0 + c + 2][r] = v4.z;
                Kt[c0 + c + 3][r] = v4.w;
            }
        }
        __syncthreads();

        float s[4][4] = {};
        #pragma unroll 8
        for (int d = 0; d < 64; d++) {
            float4 a4 = *reinterpret_cast<const float4*>(&Qt[d][ty * 4]);
            float4 b4 = *reinterpret_cast<const float4*>(&Kt[d][tx * 4]);
            float a[4] = {a4.x, a4.y, a4.z, a4.w};
            float bq[4] = {b4.x, b4.y, b4.z, b4.w};
            #pragma unroll
            for (int i = 0; i < 4; i++)
                #pragma unroll
                for (int j = 0; j < 4; j++)
                    s[i][j] += a[i] * bq[j];
        }
        #pragma unroll
        for (int i = 0; i < 4; i++) {
            float sv[4], tmax;
            #pragma unroll
            for (int j = 0; j < 4; j++)
                sv[j] = s[i][j] * scale + madd[kt2 * 64 + tx * 4 + j];
            tmax = fmaxf(fmaxf(sv[0], sv[1]), fmaxf(sv[2], sv[3]));
            float nm = fmaxf(mrow[i], tmax);
            float acc = lrow[i] * __expf(mrow[i] - nm);
            #pragma unroll
            for (int j = 0; j < 4; j++) acc += __expf(sv[j] - nm);
            lrow[i] = acc;
            mrow[i] = nm;
        }
        __syncthreads();
    }

    #pragma unroll
    for (int off = 1; off < 16; off <<= 1) {
        #pragma unroll
        for (int i = 0; i < 4; i++) {
            float m2 = __shfl_xor(mrow[i], off);
            float l2 = __shfl_xor(lrow[i], off);
            float nm = fmaxf(mrow[i], m2);
            lrow[i] = lrow[i] * __expf(mrow[i] - nm) + l2 * __expf(m2 - nm);
            mrow[i] = nm;
        }
    }
    float inv[4];
    #pragma unroll
    for (int i = 0; i < 4; i++) inv[i] = 1.0f / lrow[i];

    float cacc[4][4] = {};
    const size_t arow0 = ((size_t)((b * LN_LAYERS + layer) * HN + hh) * SS + (q0 + ty * 4)) * SS;

    for (int kt2 = 0; kt2 < 8; kt2++) {
        {
            int r = tid >> 2;
            int c0 = (tid & 3) * 16;
            const float* gpk = kb + (size_t)(b * SS + kt2 * 64 + r) * (HN * DK) + hh * DK + c0;
            const float* gpv = vb + (size_t)(b * SS + kt2 * 64 + r) * (HN * DK) + hh * DK + c0;
            #pragma unroll
            for (int c = 0; c < 16; c += 4) {
                float4 v4 = *reinterpret_cast<const float4*>(gpk + c);
                Kt[c0 + c + 0][r] = v4.x;
                Kt[c0 + c + 1][r] = v4.y;
                Kt[c0 + c + 2][r] = v4.z;
                Kt[c0 + c + 3][r] = v4.w;
                *reinterpret_cast<float4*>(&Vs[r][c0 + c]) = *reinterpret_cast<const float4*>(gpv + c);
            }
        }
        __syncthreads();

        float s[4][4] = {};
        #pragma unroll 8
        for (int d = 0; d < 64; d++) {
            float4 a4 = *reinterpret_cast<const float4*>(&Qt[d][ty * 4]);
            float4 b4 = *reinterpret_cast<const float4*>(&Kt[d][tx * 4]);
            float a[4] = {a4.x, a4.y, a4.z, a4.w};
            float bq[4] = {b4.x, b4.y, b4.z, b4.w};
            #pragma unroll
            for (int i = 0; i < 4; i++)
                #pragma unroll
                for (int j = 0; j < 4; j++)
                    s[i][j] += a[i] * bq[j];
        }
        #pragma unroll
        for (int i = 0; i < 4; i++) {
            float4 pv;
            pv.x = __expf(s[i][0] * scale + madd[kt2 * 64 + tx * 4 + 0] - mrow[i]) * inv[i];
            pv.y = __expf(s[i][1] * scale + madd[kt2 * 64 + tx * 4 + 1] - mrow[i]) * inv[i];
            pv.z = __expf(s[i][2] * scale + madd[kt2 * 64 + tx * 4 + 2] - mrow[i]) * inv[i];
            pv.w = __expf(s[i][3] * scale + madd[kt2 * 64 + tx * 4 + 3] - mrow[i]) * inv[i];
            *reinterpret_cast<float4*>(&attn_out[arow0 + (size_t)i * SS + kt2 * 64 + tx * 4]) = pv;
            *reinterpret_cast<float4*>(&Ps[ty * 4 + i][tx * 4]) = pv;
        }
        __syncthreads();

        #pragma unroll 4
        for (int kk4 = 0; kk4 < 16; kk4++) {
            float4 aq[4], bq[4];
            #pragma unroll
            for (int i = 0; i < 4; i++)
                aq[i] = *reinterpret_cast<const float4*>(&Ps[ty * 4 + i][kk4 * 4]);
            #pragma unroll
            for (int e = 0; e < 4; e++)
                bq[e] = *reinterpret_cast<const float4*>(&Vs[kk4 * 4 + e][tx * 4]);
            #pragma unroll
            for (int i = 0; i < 4; i++) {
                float av[4] = {aq[i].x, aq[i].y, aq[i].z, aq[i].w};
                #pragma unroll
                for (int e = 0; e < 4; e++) {
                    cacc[i][0] += av[e] * bq[e].x;
                    cacc[i][1] += av[e] * bq[e].y;
                    cacc[i][2] += av[e] * bq[e].z;
                    cacc[i][3] += av[e] * bq[e].w;
                }
            }
        }
        __syncthreads();
    }

    #pragma unroll
    for (int i = 0; i < 4; i++) {
        float4 cv = make_float4(cacc[i][0], cacc[i][1], cacc[i][2], cacc[i][3]);
        *reinterpret_cast<float4*>(&ctx[(size_t)(b * SS + q0 + ty * 4 + i) * (HN * DK) + hh * DK + tx * 4]) = cv;
    }
}

// ---------------------------------------------------------------------------
// LayerNorm over D=512: one block (256 threads) per row.
// ---------------------------------------------------------------------------
__global__ void ln_kernel(const float* __restrict__ in, const float* __restrict__ g,
                          const float* __restrict__ bb, float* __restrict__ out) {
    const int row = blockIdx.x;
    const int tid = threadIdx.x;
    const float* r = in + (size_t)row * DM;
    float v0 = r[tid], v1 = r[tid + 256];

    __shared__ float red[4];
    float t = v0 + v1;
    #pragma unroll
    for (int off = 32; off; off >>= 1) t += __shfl_xor(t, off);
    if ((tid & 63) == 0) red[tid >> 6] = t;
    __syncthreads();
    float mean = (red[0] + red[1] + red[2] + red[3]) * (1.0f / 512.0f);

    float d0 = v0 - mean, d1 = v1 - mean;
    float t2 = d0 * d0 + d1 * d1;
    #pragma unroll
    for (int off = 32; off; off >>= 1) t2 += __shfl_xor(t2, off);
    __syncthreads();
    if ((tid & 63) == 0) red[tid >> 6] = t2;
    __syncthreads();
    float var = (red[0] + red[1] + red[2] + red[3]) * (1.0f / 512.0f);
    float rs = 1.0f / sqrtf(var + 1e-5f);

    out[(size_t)row * DM + tid]       = d0 * rs * g[tid] + bb[tid];
    out[(size_t)row * DM + tid + 256] = d1 * rs * g[tid + 256] + bb[tid + 256];
}

// ---------------------------------------------------------------------------
extern "C" void kernel_launch(void* const* d_in, const int* in_sizes, int n_in,
                              void* d_out, int out_size, void* d_ws, size_t ws_size,
                              hipStream_t stream) {
    const int*   x    = (const int*)d_in[0];
    const float* emb  = (const float*)d_in[1];
    const float* pe   = (const float*)d_in[2];
    const float* WQ   = (const float*)d_in[3];
    const float* bQ   = (const float*)d_in[4];
    const float* WK   = (const float*)d_in[5];
    const float* bK   = (const float*)d_in[6];
    const float* WV   = (const float*)d_in[7];
    const float* bV   = (const float*)d_in[8];
    const float* WO   = (const float*)d_in[9];
    const float* bO   = (const float*)d_in[10];
    const float* ln1g = (const float*)d_in[11];
    const float* ln1b = (const float*)d_in[12];
    const float* W1   = (const float*)d_in[13];
    const float* b1   = (const float*)d_in[14];
    const float* W2   = (const float*)d_in[15];
    const float* b2   = (const float*)d_in[16];
    const float* ln2g = (const float*)d_in[17];
    const float* ln2b = (const float*)d_in[18];

    float* out = (float*)d_out;
    const size_t HSIZE = (size_t)MROWS * DM;
    float* attn_base = out + HSIZE;

    float* ws  = (float*)d_ws;
    float* h   = ws;
    float* tmp = h   + HSIZE;
    float* qb  = tmp + HSIZE;
    float* kb  = qb  + HSIZE;
    float* vb  = kb  + HSIZE;
    float* ctx = vb  + HSIZE;
    float* ff  = ctx + HSIZE;

    embed_kernel<<<(MROWS * DM) / 256, 256, 0, stream>>>(x, emb, pe, h);

    dim3 gQKV(DM / 64, MROWS / 32, 3);   // 8 x 64 x 3
    dim3 gD(DM / 64, MROWS / 32);        // 8 x 64 = 512 blocks
    dim3 gF(DFF / 64, MROWS / 32);       // 32 x 64 = 2048 blocks

    for (int i = 0; i < LN_LAYERS; i++) {
        const float* wq = WQ + (size_t)i * DM * (HN * DK);
        const float* wk = WK + (size_t)i * DM * (HN * DK);
        const float* wv = WV + (size_t)i * DM * (HN * DK);
        const float* wo = WO + (size_t)i * (HN * DK) * DM;

        gemm3_qkv<<<gQKV, 128, 0, stream>>>(h, wq, wk, wv,
                bQ + i * (HN * DK), bK + i * (HN * DK), bV + i * (HN * DK),
                qb, kb, vb, DM);

        attn_kernel<<<BB * HN * (SS / 64), 256, 0, stream>>>(qb, kb, vb, x, attn_base, ctx, i);

        gemm3_kernel<2><<<gD, 128, 0, stream>>>(ctx, wo, bO + i * DM, h, tmp, DM, DM);
        ln_kernel<<<MROWS, 256, 0, stream>>>(tmp, ln1g + i * DM, ln1b + i * DM, h);

        gemm3_kernel<1><<<gF, 128, 0, stream>>>(h, W1 + (size_t)i * DM * DFF, b1 + i * DFF, nullptr, ff, DFF, DM);
        gemm3_kernel<2><<<gD, 128, 0, stream>>>(ff, W2 + (size_t)i * DFF * DM, b2 + i * DM, h, tmp, DM, DFF);
        ln_kernel<<<MROWS, 256, 0, stream>>>(tmp, ln2g + i * DM, ln2b + i * DM, h);
    }

    hipMemcpyAsync(out, h, HSIZE * sizeof(float), hipMemcpyDeviceToDevice, stream);
}

// Round 4
// 1347.359 us; speedup vs baseline: 3.5016x; 1.2720x over previous
//
#include <hip/hip_runtime.h>
#include <math.h>

// Problem constants (fixed by the reference)
#define BB 4
#define SS 512
#define DM 512
#define HN 8
#define DK 64
#define LN_LAYERS 6
#define DFF 2048
#define MROWS 2048

typedef float f32x4 __attribute__((ext_vector_type(4)));
typedef short s16x8 __attribute__((ext_vector_type(8)));
typedef unsigned short u16;

__device__ __forceinline__ u16 bf16_rtne(float f) {
    unsigned u = __float_as_uint(f);
    unsigned r = u + 0x7FFFu + ((u >> 16) & 1u);
    return (u16)(r >> 16);
}
__device__ __forceinline__ void split2(float a, u16& hi, u16& lo) {
    u16 h = bf16_rtne(a);
    hi = h;
    float fh = __uint_as_float(((unsigned)h) << 16);
    lo = bf16_rtne(a - fh);
}

// async global->LDS, 16B per lane; lds base must be wave-uniform (HW adds lane*16)
__device__ __forceinline__ void gl16(const void* g, void* l) {
    __builtin_amdgcn_global_load_lds(
        (const __attribute__((address_space(1))) unsigned int*)g,
        (__attribute__((address_space(3))) unsigned int*)l,
        16, 0, 0);
}

// ---------------------------------------------------------------------------
// Embedding: h = emb[x] + pe, writes fp32 + bf16 hi/lo splits
// ---------------------------------------------------------------------------
__global__ void embed_kernel(const int* __restrict__ x, const float* __restrict__ emb,
                             const float* __restrict__ pe, float* __restrict__ h,
                             u16* __restrict__ hhi, u16* __restrict__ hlo) {
    int idx = blockIdx.x * blockDim.x + threadIdx.x;
    int d = idx & (DM - 1);
    int bs = idx / DM;
    int s = bs & (SS - 1);
    int tok = x[bs];
    float v = emb[(size_t)tok * DM + d] + pe[s * DM + d];
    h[idx] = v;
    u16 hh, ll; split2(v, hh, ll);
    hhi[idx] = hh;
    hlo[idx] = ll;
}

// ---------------------------------------------------------------------------
// Weight prep: transpose + split all layer weights into bf16 hi/lo [N][K].
// 768 tiles/layer: wq(64) wk(64) wv(64) wo(64) w1(256) w2(256); 64x64 tiles.
// ---------------------------------------------------------------------------
__global__ __launch_bounds__(256) void prep_kernel(
        const float* __restrict__ WQ, const float* __restrict__ WK,
        const float* __restrict__ WV, const float* __restrict__ WO,
        const float* __restrict__ W1, const float* __restrict__ W2,
        u16* __restrict__ whi, u16* __restrict__ wlo) {
    __shared__ float T[64][68];
    const int bid = blockIdx.x;
    const int layer = bid / 768;
    const int r = bid % 768;
    const float* src; int Ks, Ns; size_t doff; int tt;
    if (r < 64)       { src = WQ + (size_t)layer * 512 * 512;  Ks = 512;  Ns = 512;  doff = 0;       tt = r; }
    else if (r < 128) { src = WK + (size_t)layer * 512 * 512;  Ks = 512;  Ns = 512;  doff = 262144;  tt = r - 64; }
    else if (r < 192) { src = WV + (size_t)layer * 512 * 512;  Ks = 512;  Ns = 512;  doff = 524288;  tt = r - 128; }
    else if (r < 256) { src = WO + (size_t)layer * 512 * 512;  Ks = 512;  Ns = 512;  doff = 786432;  tt = r - 192; }
    else if (r < 512) { src = W1 + (size_t)layer * 512 * 2048; Ks = 512;  Ns = 2048; doff = 1048576; tt = r - 256; }
    else              { src = W2 + (size_t)layer * 2048 * 512; Ks = 2048; Ns = 512;  doff = 2097152; tt = r - 512; }
    u16* dh = whi + (size_t)layer * 3145728 + doff;
    u16* dl = wlo + (size_t)layer * 3145728 + doff;
    const int tn = tt % (Ns / 64), tk = tt / (Ns / 64);
    const int t = threadIdx.x;

    #pragma unroll
    for (int it = 0; it < 4; it++) {
        int rl = (t >> 4) + it * 16;
        int cl = (t & 15) * 4;
        float4 v = *reinterpret_cast<const float4*>(&src[(size_t)(tk * 64 + rl) * Ns + tn * 64 + cl]);
        T[rl][cl] = v.x; T[rl][cl + 1] = v.y; T[rl][cl + 2] = v.z; T[rl][cl + 3] = v.w;
    }
    __syncthreads();
    #pragma unroll
    for (int it = 0; it < 4; it++) {
        int nl = (t >> 4) + it * 16;
        int kl = (t & 15) * 4;
        ushort4 h4, l4;
        u16 hh, ll;
        split2(T[kl + 0][nl], hh, ll); h4.x = hh; l4.x = ll;
        split2(T[kl + 1][nl], hh, ll); h4.y = hh; l4.y = ll;
        split2(T[kl + 2][nl], hh, ll); h4.z = hh; l4.z = ll;
        split2(T[kl + 3][nl], hh, ll); h4.w = hh; l4.w = ll;
        size_t o = (size_t)(tn * 64 + nl) * Ks + tk * 64 + kl;
        *reinterpret_cast<ushort4*>(&dh[o]) = h4;
        *reinterpret_cast<ushort4*>(&dl[o]) = l4;
    }
}

// ---------------------------------------------------------------------------
// bf16x3 MFMA GEMM, pre-split operands. A: [M,K] hi/lo bf16; B: [N,K] hi/lo
// (pre-transposed). Tile 64x64, BK=64, 256 threads (4 waves, 2x2 wave grid).
// LDS linear + XOR swizzle (byte ^= (row&7)<<4) with pre-swizzled global src.
//   EPI 0: C=acc+bias fp32; EPI 1: GELU -> Chi/Clo bf16 split; EPI 2: +R fp32.
// ---------------------------------------------------------------------------
template <int EPI>
__device__ __forceinline__ void bgemm_body(
        const u16* __restrict__ Ah, const u16* __restrict__ Al,
        const u16* __restrict__ Bh, const u16* __restrict__ Bl,
        const float* __restrict__ bias, const float* __restrict__ R,
        float* __restrict__ C, u16* __restrict__ Chi, u16* __restrict__ Clo,
        int N, int K, int m0, int n0) {
    __shared__ u16 sAh[64 * 64], sAl[64 * 64], sBh[64 * 64], sBl[64 * 64];
    const int t = threadIdx.x;
    const int lane = t & 63, w = t >> 6;
    const int lr = lane & 15, lg = lane >> 4;
    const int wm = (w >> 1) * 32, wn = (w & 1) * 32;

    // staging geometry: issue i covers LDS rows (w*2+i)*8 .. +8 (1024 B)
    const int rr = lane >> 3;                          // 0..7 (row within 8-row stripe)
    const int kbs = ((lane & 7) << 4) ^ (rr << 4);     // pre-swizzled byte-in-row
    const int row0 = (w * 2 + 0) * 8 + rr;
    const int row1 = (w * 2 + 1) * 8 + rr;
    const int lds0 = (w * 2 + 0) * 512;                // u16 units (1024 B)
    const int lds1 = (w * 2 + 1) * 512;

    f32x4 acc[2][2] = {};

    for (int k0 = 0; k0 < K; k0 += 64) {
        size_t a0 = ((size_t)(m0 + row0) * K + k0) * 2 + kbs;
        size_t a1 = ((size_t)(m0 + row1) * K + k0) * 2 + kbs;
        size_t b0 = ((size_t)(n0 + row0) * K + k0) * 2 + kbs;
        size_t b1 = ((size_t)(n0 + row1) * K + k0) * 2 + kbs;
        gl16((const char*)Ah + a0, sAh + lds0);
        gl16((const char*)Ah + a1, sAh + lds1);
        gl16((const char*)Al + a0, sAl + lds0);
        gl16((const char*)Al + a1, sAl + lds1);
        gl16((const char*)Bh + b0, sBh + lds0);
        gl16((const char*)Bh + b1, sBh + lds1);
        gl16((const char*)Bl + b0, sBl + lds0);
        gl16((const char*)Bl + b1, sBl + lds1);
        __syncthreads();   // compiler drains vmcnt before s_barrier

        #pragma unroll
        for (int kc = 0; kc < 2; kc++) {
            const int kb = kc * 64 + lg * 16;
            s16x8 a_h[2], a_l[2], b_h[2], b_l[2];
            #pragma unroll
            for (int f = 0; f < 2; f++) {
                int ra = wm + f * 16 + lr;
                int rb = wn + f * 16 + lr;
                int oa = ra * 128 + (kb ^ ((ra & 7) << 4));
                int ob = rb * 128 + (kb ^ ((rb & 7) << 4));
                a_h[f] = *reinterpret_cast<const s16x8*>((const char*)sAh + oa);
                a_l[f] = *reinterpret_cast<const s16x8*>((const char*)sAl + oa);
                b_h[f] = *reinterpret_cast<const s16x8*>((const char*)sBh + ob);
                b_l[f] = *reinterpret_cast<const s16x8*>((const char*)sBl + ob);
            }
            #pragma unroll
            for (int fm = 0; fm < 2; fm++)
                #pragma unroll
                for (int fn = 0; fn < 2; fn++) {
                    acc[fm][fn] = __builtin_amdgcn_mfma_f32_16x16x32_bf16(a_h[fm], b_l[fn], acc[fm][fn], 0, 0, 0);
                    acc[fm][fn] = __builtin_amdgcn_mfma_f32_16x16x32_bf16(a_l[fm], b_h[fn], acc[fm][fn], 0, 0, 0);
                    acc[fm][fn] = __builtin_amdgcn_mfma_f32_16x16x32_bf16(a_h[fm], b_h[fn], acc[fm][fn], 0, 0, 0);
                }
        }
        __syncthreads();
    }

    #pragma unroll
    for (int fm = 0; fm < 2; fm++) {
        #pragma unroll
        for (int fn = 0; fn < 2; fn++) {
            int col = n0 + wn + fn * 16 + lr;
            float bv = bias[col];
            #pragma unroll
            for (int r4 = 0; r4 < 4; r4++) {
                int row = m0 + wm + fm * 16 + lg * 4 + r4;
                float v = acc[fm][fn][r4] + bv;
                if (EPI == 1) {
                    float u = v + 0.044715f * v * v * v;
                    float z2 = 1.5957691216057308f * u;      // 2*sqrt(2/pi)*u
                    float ax = fabsf(z2);
                    float e = __expf(ax);
                    float th = 1.0f - 2.0f / (e + 1.0f);
                    th = (z2 < 0.0f) ? -th : th;
                    v = 0.5f * v * (1.0f + th);
                    u16 hh, ll; split2(v, hh, ll);
                    Chi[(size_t)row * N + col] = hh;
                    Clo[(size_t)row * N + col] = ll;
                } else {
                    if (EPI == 2) v += R[(size_t)row * N + col];
                    C[(size_t)row * N + col] = v;
                }
            }
        }
    }
}

template <int EPI>
__global__ __launch_bounds__(256) void bgemm_kernel(
        const u16* __restrict__ Ah, const u16* __restrict__ Al,
        const u16* __restrict__ Bh, const u16* __restrict__ Bl,
        const float* __restrict__ bias, const float* __restrict__ R,
        float* __restrict__ C, u16* __restrict__ Chi, u16* __restrict__ Clo,
        int N, int K) {
    bgemm_body<EPI>(Ah, Al, Bh, Bl, bias, R, C, Chi, Clo, N, K, blockIdx.y * 64, blockIdx.x * 64);
}

__global__ __launch_bounds__(256) void bgemm_qkv(
        const u16* __restrict__ Ah, const u16* __restrict__ Al,
        const u16* __restrict__ Wh, const u16* __restrict__ Wl,
        const float* __restrict__ bQ, const float* __restrict__ bK, const float* __restrict__ bV,
        float* __restrict__ qb, float* __restrict__ kb, float* __restrict__ vb) {
    const int z = blockIdx.z;
    const u16* Bh = Wh + (size_t)z * 262144;
    const u16* Bl = Wl + (size_t)z * 262144;
    const float* bias = (z == 0) ? bQ : (z == 1) ? bK : bV;
    float* C = (z == 0) ? qb : (z == 1) ? kb : vb;
    bgemm_body<0>(Ah, Al, Bh, Bl, bias, nullptr, C, nullptr, nullptr, DM, DM,
                  blockIdx.y * 64, blockIdx.x * 64);
}

// ---------------------------------------------------------------------------
// Attention: tiled two-pass flash-style; ctx now written as bf16 hi/lo splits.
// ---------------------------------------------------------------------------
__global__ __launch_bounds__(256) void attn_kernel(
        const float* __restrict__ qb, const float* __restrict__ kb,
        const float* __restrict__ vb, const int* __restrict__ x,
        float* __restrict__ attn_out, u16* __restrict__ ctx_hi, u16* __restrict__ ctx_lo,
        int layer) {
    const int bid = blockIdx.x;
    const int qt = bid & 7;
    const int hh = (bid >> 3) & 7;
    const int b  = bid >> 6;
    const int tid = threadIdx.x;
    const int tx = tid & 15;
    const int ty = tid >> 4;
    const int q0 = qt * 64;

    __shared__ float Qt[64][68];
    __shared__ float Kt[64][68];
    __shared__ float Vs[64][68];
    __shared__ float Ps[64][68];
    __shared__ float madd[SS];

    madd[tid]       = (x[b * SS + tid] == 0)       ? -1e9f : 0.0f;
    madd[tid + 256] = (x[b * SS + tid + 256] == 0) ? -1e9f : 0.0f;

    {
        int r = tid >> 2;
        int c0 = (tid & 3) * 16;
        const float* gp = qb + (size_t)(b * SS + q0 + r) * (HN * DK) + hh * DK + c0;
        #pragma unroll
        for (int c = 0; c < 16; c += 4) {
            float4 v4 = *reinterpret_cast<const float4*>(gp + c);
            Qt[c0 + c + 0][r] = v4.x;
            Qt[c0 + c + 1][r] = v4.y;
            Qt[c0 + c + 2][r] = v4.z;
            Qt[c0 + c + 3][r] = v4.w;
        }
    }
    __syncthreads();

    const float scale = 0.125f;
    float mrow[4], lrow[4];
    #pragma unroll
    for (int i = 0; i < 4; i++) { mrow[i] = -1e30f; lrow[i] = 0.0f; }

    for (int kt2 = 0; kt2 < 8; kt2++) {
        {
            int r = tid >> 2;
            int c0 = (tid & 3) * 16;
            const float* gp = kb + (size_t)(b * SS + kt2 * 64 + r) * (HN * DK) + hh * DK + c0;
            #pragma unroll
            for (int c = 0; c < 16; c += 4) {
                float4 v4 = *reinterpret_cast<const float4*>(gp + c);
                Kt[c0 + c + 0][r] = v4.x;
                Kt[c0 + c + 1][r] = v4.y;
                Kt[c0 + c + 2][r] = v4.z;
                Kt[c0 + c + 3][r] = v4.w;
            }
        }
        __syncthreads();

        float s[4][4] = {};
        #pragma unroll 8
        for (int d = 0; d < 64; d++) {
            float4 a4 = *reinterpret_cast<const float4*>(&Qt[d][ty * 4]);
            float4 b4 = *reinterpret_cast<const float4*>(&Kt[d][tx * 4]);
            float a[4] = {a4.x, a4.y, a4.z, a4.w};
            float bq[4] = {b4.x, b4.y, b4.z, b4.w};
            #pragma unroll
            for (int i = 0; i < 4; i++)
                #pragma unroll
                for (int j = 0; j < 4; j++)
                    s[i][j] += a[i] * bq[j];
        }
        #pragma unroll
        for (int i = 0; i < 4; i++) {
            float sv[4], tmax;
            #pragma unroll
            for (int j = 0; j < 4; j++)
                sv[j] = s[i][j] * scale + madd[kt2 * 64 + tx * 4 + j];
            tmax = fmaxf(fmaxf(sv[0], sv[1]), fmaxf(sv[2], sv[3]));
            float nm = fmaxf(mrow[i], tmax);
            float acc = lrow[i] * __expf(mrow[i] - nm);
            #pragma unroll
            for (int j = 0; j < 4; j++) acc += __expf(sv[j] - nm);
            lrow[i] = acc;
            mrow[i] = nm;
        }
        __syncthreads();
    }

    #pragma unroll
    for (int off = 1; off < 16; off <<= 1) {
        #pragma unroll
        for (int i = 0; i < 4; i++) {
            float m2 = __shfl_xor(mrow[i], off);
            float l2 = __shfl_xor(lrow[i], off);
            float nm = fmaxf(mrow[i], m2);
            lrow[i] = lrow[i] * __expf(mrow[i] - nm) + l2 * __expf(m2 - nm);
            mrow[i] = nm;
        }
    }
    float inv[4];
    #pragma unroll
    for (int i = 0; i < 4; i++) inv[i] = 1.0f / lrow[i];

    float cacc[4][4] = {};
    const size_t arow0 = ((size_t)((b * LN_LAYERS + layer) * HN + hh) * SS + (q0 + ty * 4)) * SS;

    for (int kt2 = 0; kt2 < 8; kt2++) {
        {
            int r = tid >> 2;
            int c0 = (tid & 3) * 16;
            const float* gpk = kb + (size_t)(b * SS + kt2 * 64 + r) * (HN * DK) + hh * DK + c0;
            const float* gpv = vb + (size_t)(b * SS + kt2 * 64 + r) * (HN * DK) + hh * DK + c0;
            #pragma unroll
            for (int c = 0; c < 16; c += 4) {
                float4 v4 = *reinterpret_cast<const float4*>(gpk + c);
                Kt[c0 + c + 0][r] = v4.x;
                Kt[c0 + c + 1][r] = v4.y;
                Kt[c0 + c + 2][r] = v4.z;
                Kt[c0 + c + 3][r] = v4.w;
                *reinterpret_cast<float4*>(&Vs[r][c0 + c]) = *reinterpret_cast<const float4*>(gpv + c);
            }
        }
        __syncthreads();

        float s[4][4] = {};
        #pragma unroll 8
        for (int d = 0; d < 64; d++) {
            float4 a4 = *reinterpret_cast<const float4*>(&Qt[d][ty * 4]);
            float4 b4 = *reinterpret_cast<const float4*>(&Kt[d][tx * 4]);
            float a[4] = {a4.x, a4.y, a4.z, a4.w};
            float bq[4] = {b4.x, b4.y, b4.z, b4.w};
            #pragma unroll
            for (int i = 0; i < 4; i++)
                #pragma unroll
                for (int j = 0; j < 4; j++)
                    s[i][j] += a[i] * bq[j];
        }
        #pragma unroll
        for (int i = 0; i < 4; i++) {
            float4 pv;
            pv.x = __expf(s[i][0] * scale + madd[kt2 * 64 + tx * 4 + 0] - mrow[i]) * inv[i];
            pv.y = __expf(s[i][1] * scale + madd[kt2 * 64 + tx * 4 + 1] - mrow[i]) * inv[i];
            pv.z = __expf(s[i][2] * scale + madd[kt2 * 64 + tx * 4 + 2] - mrow[i]) * inv[i];
            pv.w = __expf(s[i][3] * scale + madd[kt2 * 64 + tx * 4 + 3] - mrow[i]) * inv[i];
            *reinterpret_cast<float4*>(&attn_out[arow0 + (size_t)i * SS + kt2 * 64 + tx * 4]) = pv;
            *reinterpret_cast<float4*>(&Ps[ty * 4 + i][tx * 4]) = pv;
        }
        __syncthreads();

        #pragma unroll 4
        for (int kk4 = 0; kk4 < 16; kk4++) {
            float4 aq[4], bq[4];
            #pragma unroll
            for (int i = 0; i < 4; i++)
                aq[i] = *reinterpret_cast<const float4*>(&Ps[ty * 4 + i][kk4 * 4]);
            #pragma unroll
            for (int e = 0; e < 4; e++)
                bq[e] = *reinterpret_cast<const float4*>(&Vs[kk4 * 4 + e][tx * 4]);
            #pragma unroll
            for (int i = 0; i < 4; i++) {
                float av[4] = {aq[i].x, aq[i].y, aq[i].z, aq[i].w};
                #pragma unroll
                for (int e = 0; e < 4; e++) {
                    cacc[i][0] += av[e] * bq[e].x;
                    cacc[i][1] += av[e] * bq[e].y;
                    cacc[i][2] += av[e] * bq[e].z;
                    cacc[i][3] += av[e] * bq[e].w;
                }
            }
        }
        __syncthreads();
    }

    #pragma unroll
    for (int i = 0; i < 4; i++) {
        ushort4 h4, l4;
        u16 hh2, ll2;
        split2(cacc[i][0], hh2, ll2); h4.x = hh2; l4.x = ll2;
        split2(cacc[i][1], hh2, ll2); h4.y = hh2; l4.y = ll2;
        split2(cacc[i][2], hh2, ll2); h4.z = hh2; l4.z = ll2;
        split2(cacc[i][3], hh2, ll2); h4.w = hh2; l4.w = ll2;
        size_t o = (size_t)(b * SS + q0 + ty * 4 + i) * (HN * DK) + hh * DK + tx * 4;
        *reinterpret_cast<ushort4*>(&ctx_hi[o]) = h4;
        *reinterpret_cast<ushort4*>(&ctx_lo[o]) = l4;
    }
}

// ---------------------------------------------------------------------------
// LayerNorm over D=512: writes fp32 + bf16 hi/lo splits.
// ---------------------------------------------------------------------------
__global__ void ln_kernel(const float* __restrict__ in, const float* __restrict__ g,
                          const float* __restrict__ bb, float* __restrict__ out,
                          u16* __restrict__ ohi, u16* __restrict__ olo) {
    const int row = blockIdx.x;
    const int tid = threadIdx.x;
    const float* r = in + (size_t)row * DM;
    float v0 = r[tid], v1 = r[tid + 256];

    __shared__ float red[4];
    float t = v0 + v1;
    #pragma unroll
    for (int off = 32; off; off >>= 1) t += __shfl_xor(t, off);
    if ((tid & 63) == 0) red[tid >> 6] = t;
    __syncthreads();
    float mean = (red[0] + red[1] + red[2] + red[3]) * (1.0f / 512.0f);

    float d0 = v0 - mean, d1 = v1 - mean;
    float t2 = d0 * d0 + d1 * d1;
    #pragma unroll
    for (int off = 32; off; off >>= 1) t2 += __shfl_xor(t2, off);
    __syncthreads();
    if ((tid & 63) == 0) red[tid >> 6] = t2;
    __syncthreads();
    float var = (red[0] + red[1] + red[2] + red[3]) * (1.0f / 512.0f);
    float rs = 1.0f / sqrtf(var + 1e-5f);

    float o0 = d0 * rs * g[tid] + bb[tid];
    float o1 = d1 * rs * g[tid + 256] + bb[tid + 256];
    size_t base = (size_t)row * DM;
    out[base + tid] = o0;
    out[base + tid + 256] = o1;
    u16 hh, ll;
    split2(o0, hh, ll); ohi[base + tid] = hh;       olo[base + tid] = ll;
    split2(o1, hh, ll); ohi[base + tid + 256] = hh; olo[base + tid + 256] = ll;
}

// ---------------------------------------------------------------------------
extern "C" void kernel_launch(void* const* d_in, const int* in_sizes, int n_in,
                              void* d_out, int out_size, void* d_ws, size_t ws_size,
                              hipStream_t stream) {
    const int*   x    = (const int*)d_in[0];
    const float* emb  = (const float*)d_in[1];
    const float* pe   = (const float*)d_in[2];
    const float* WQ   = (const float*)d_in[3];
    const float* bQ   = (const float*)d_in[4];
    const float* WK   = (const float*)d_in[5];
    const float* bK   = (const float*)d_in[6];
    const float* WV   = (const float*)d_in[7];
    const float* bV   = (const float*)d_in[8];
    const float* WO   = (const float*)d_in[9];
    const float* bO   = (const float*)d_in[10];
    const float* ln1g = (const float*)d_in[11];
    const float* ln1b = (const float*)d_in[12];
    const float* W1   = (const float*)d_in[13];
    const float* b1   = (const float*)d_in[14];
    const float* W2   = (const float*)d_in[15];
    const float* b2   = (const float*)d_in[16];
    const float* ln2g = (const float*)d_in[17];
    const float* ln2b = (const float*)d_in[18];

    float* out = (float*)d_out;
    const size_t HSIZE = (size_t)MROWS * DM;   // 1,048,576
    float* attn_base = out + HSIZE;

    // workspace: fp32 region then bf16 (u16) region
    float* ws  = (float*)d_ws;
    float* h   = ws;                  // [2048,512]
    float* tmp = h   + HSIZE;
    float* qb  = tmp + HSIZE;
    float* kb  = qb  + HSIZE;
    float* vb  = kb  + HSIZE;
    u16* us     = (u16*)(vb + HSIZE);
    u16* h_hi   = us;                         // 1M
    u16* h_lo   = h_hi   + HSIZE;
    u16* ctx_hi = h_lo   + HSIZE;
    u16* ctx_lo = ctx_hi + HSIZE;
    u16* ff_hi  = ctx_lo + HSIZE;             // 4M
    u16* ff_lo  = ff_hi  + (size_t)MROWS * DFF;
    u16* w_hi   = ff_lo  + (size_t)MROWS * DFF;   // 6 * 3,145,728
    u16* w_lo   = w_hi   + (size_t)LN_LAYERS * 3145728;

    prep_kernel<<<LN_LAYERS * 768, 256, 0, stream>>>(WQ, WK, WV, WO, W1, W2, w_hi, w_lo);
    embed_kernel<<<(MROWS * DM) / 256, 256, 0, stream>>>(x, emb, pe, h, h_hi, h_lo);

    dim3 gQKV(DM / 64, MROWS / 64, 3);   // 8 x 32 x 3
    dim3 gD(DM / 64, MROWS / 64);        // 8 x 32
    dim3 gF(DFF / 64, MROWS / 64);       // 32 x 32

    for (int i = 0; i < LN_LAYERS; i++) {
        const u16* lwh = w_hi + (size_t)i * 3145728;
        const u16* lwl = w_lo + (size_t)i * 3145728;

        bgemm_qkv<<<gQKV, 256, 0, stream>>>(h_hi, h_lo, lwh, lwl,
                bQ + i * DM, bK + i * DM, bV + i * DM, qb, kb, vb);

        attn_kernel<<<BB * HN * (SS / 64), 256, 0, stream>>>(qb, kb, vb, x,
                attn_base, ctx_hi, ctx_lo, i);

        bgemm_kernel<2><<<gD, 256, 0, stream>>>(ctx_hi, ctx_lo,
                lwh + 786432, lwl + 786432, bO + i * DM, h, tmp, nullptr, nullptr, DM, DM);
        ln_kernel<<<MROWS, 256, 0, stream>>>(tmp, ln1g + i * DM, ln1b + i * DM, h, h_hi, h_lo);

        bgemm_kernel<1><<<gF, 256, 0, stream>>>(h_hi, h_lo,
                lwh + 1048576, lwl + 1048576, b1 + i * DFF, nullptr,
                nullptr, ff_hi, ff_lo, DFF, DM);
        bgemm_kernel<2><<<gD, 256, 0, stream>>>(ff_hi, ff_lo,
                lwh + 2097152, lwl + 2097152, b2 + i * DM, h, tmp, nullptr, nullptr, DM, DFF);
        ln_kernel<<<MROWS, 256, 0, stream>>>(tmp, ln2g + i * DM, ln2b + i * DM, h, h_hi, h_lo);
    }

    hipMemcpyAsync(out, h, HSIZE * sizeof(float), hipMemcpyDeviceToDevice, stream);
}

// Round 5
// 1203.872 us; speedup vs baseline: 3.9190x; 1.1192x over previous
//
#include <hip/hip_runtime.h>
#include <math.h>

#define BB 4
#define SS 512
#define DM 512
#define HN 8
#define DK 64
#define LN_LAYERS 6
#define DFF 2048
#define MROWS 2048

typedef float f32x4 __attribute__((ext_vector_type(4)));
typedef short s16x8 __attribute__((ext_vector_type(8)));
typedef unsigned short u16;

__device__ __forceinline__ u16 bf16_rtne(float f) {
    unsigned u = __float_as_uint(f);
    unsigned r = u + 0x7FFFu + ((u >> 16) & 1u);
    return (u16)(r >> 16);
}
__device__ __forceinline__ void split2(float a, u16& hi, u16& lo) {
    u16 h = bf16_rtne(a);
    hi = h;
    float fh = __uint_as_float(((unsigned)h) << 16);
    lo = bf16_rtne(a - fh);
}

// async global->LDS, 16B/lane; lds base wave-uniform (HW adds lane*16)
__device__ __forceinline__ void gl16(const u16* g, u16* l) {
    __builtin_amdgcn_global_load_lds(
        (const __attribute__((address_space(1))) unsigned int*)g,
        (__attribute__((address_space(3))) unsigned int*)l,
        16, 0, 0);
}

// ---------------------------------------------------------------------------
// Embedding: h = emb[x] + pe  -> fp32 + bf16 hi/lo
// ---------------------------------------------------------------------------
__global__ void embed_kernel(const int* __restrict__ x, const float* __restrict__ emb,
                             const float* __restrict__ pe, float* __restrict__ h,
                             u16* __restrict__ hhi, u16* __restrict__ hlo) {
    int idx = blockIdx.x * blockDim.x + threadIdx.x;
    int d = idx & (DM - 1);
    int bs = idx / DM;
    int s = bs & (SS - 1);
    int tok = x[bs];
    float v = emb[(size_t)tok * DM + d] + pe[s * DM + d];
    h[idx] = v;
    u16 hh, ll; split2(v, hh, ll);
    hhi[idx] = hh;
    hlo[idx] = ll;
}

// ---------------------------------------------------------------------------
// Weight prep: transpose + split into bf16 hi/lo [N][K] (Q,K,V,O,W1,W2 per layer)
// ---------------------------------------------------------------------------
__global__ __launch_bounds__(256) void prep_kernel(
        const float* __restrict__ WQ, const float* __restrict__ WK,
        const float* __restrict__ WV, const float* __restrict__ WO,
        const float* __restrict__ W1, const float* __restrict__ W2,
        u16* __restrict__ whi, u16* __restrict__ wlo) {
    __shared__ float T[64][68];
    const int bid = blockIdx.x;
    const int layer = bid / 768;
    const int r = bid % 768;
    const float* src; int Ks, Ns; size_t doff; int tt;
    if (r < 64)       { src = WQ + (size_t)layer * 512 * 512;  Ks = 512;  Ns = 512;  doff = 0;       tt = r; }
    else if (r < 128) { src = WK + (size_t)layer * 512 * 512;  Ks = 512;  Ns = 512;  doff = 262144;  tt = r - 64; }
    else if (r < 192) { src = WV + (size_t)layer * 512 * 512;  Ks = 512;  Ns = 512;  doff = 524288;  tt = r - 128; }
    else if (r < 256) { src = WO + (size_t)layer * 512 * 512;  Ks = 512;  Ns = 512;  doff = 786432;  tt = r - 192; }
    else if (r < 512) { src = W1 + (size_t)layer * 512 * 2048; Ks = 512;  Ns = 2048; doff = 1048576; tt = r - 256; }
    else              { src = W2 + (size_t)layer * 2048 * 512; Ks = 2048; Ns = 512;  doff = 2097152; tt = r - 512; }
    u16* dh = whi + (size_t)layer * 3145728 + doff;
    u16* dl = wlo + (size_t)layer * 3145728 + doff;
    const int tn = tt % (Ns / 64), tk = tt / (Ns / 64);
    const int t = threadIdx.x;

    #pragma unroll
    for (int it = 0; it < 4; it++) {
        int rl = (t >> 4) + it * 16;
        int cl = (t & 15) * 4;
        float4 v = *reinterpret_cast<const float4*>(&src[(size_t)(tk * 64 + rl) * Ns + tn * 64 + cl]);
        T[rl][cl] = v.x; T[rl][cl + 1] = v.y; T[rl][cl + 2] = v.z; T[rl][cl + 3] = v.w;
    }
    __syncthreads();
    #pragma unroll
    for (int it = 0; it < 4; it++) {
        int nl = (t >> 4) + it * 16;
        int kl = (t & 15) * 4;
        ushort4 h4, l4;
        u16 hh, ll;
        split2(T[kl + 0][nl], hh, ll); h4.x = hh; l4.x = ll;
        split2(T[kl + 1][nl], hh, ll); h4.y = hh; l4.y = ll;
        split2(T[kl + 2][nl], hh, ll); h4.z = hh; l4.z = ll;
        split2(T[kl + 3][nl], hh, ll); h4.w = hh; l4.w = ll;
        size_t o = (size_t)(tn * 64 + nl) * Ks + tk * 64 + kl;
        *reinterpret_cast<ushort4*>(&dh[o]) = h4;
        *reinterpret_cast<ushort4*>(&dl[o]) = l4;
    }
}

// ---------------------------------------------------------------------------
// bf16x3 MFMA GEMM, pre-split operands, BM=128, BK=32, 4 waves (2x2).
// 64B LDS rows (32 u16) are bank-conflict-free for b128 frag reads.
// EPI 0: raw fp32 partial (split-K via blockIdx.z); EPI 1: bias+GELU->hi/lo;
// EPI 3: QKV fused (bias per segment; Q,K natural hi/lo; V transposed hi/lo).
// ---------------------------------------------------------------------------
template <int BN, int EPI>
__global__ __launch_bounds__(256) void bgemm(
        const u16* __restrict__ Ah, const u16* __restrict__ Al,
        const u16* __restrict__ Bh, const u16* __restrict__ Bl,
        const float* __restrict__ bias0, const float* __restrict__ bias1,
        const float* __restrict__ bias2,
        float* __restrict__ Cf,
        u16* __restrict__ Xhi, u16* __restrict__ Xlo,
        u16* __restrict__ Yhi, u16* __restrict__ Ylo,
        u16* __restrict__ Zhi, u16* __restrict__ Zlo,
        int N, int K, int KS) {
    constexpr int WN = BN / 2;
    constexpr int NF = WN / 16;
    __shared__ u16 sA[2][128 * 32];
    __shared__ u16 sB[2][BN * 32];
    const int t = threadIdx.x;
    const int lane = t & 63, w = t >> 6;
    const int lr = lane & 15, lg = lane >> 4;
    const int m0 = blockIdx.y * 128, n0 = blockIdx.x * BN;
    const int sk = blockIdx.z;
    const int kb0 = sk * KS;
    const int srow = lane >> 2;        // 0..15
    const int sby = (lane & 3) * 8;    // u16 offset (16B chunks)
    const int wm2 = (w >> 1), wn2 = (w & 1);

    f32x4 acc[4][NF] = {};

    for (int k0 = kb0; k0 < kb0 + KS; k0 += 32) {
        #pragma unroll
        for (int i = 0; i < 2; i++) {           // A: 32 rows per wave
            int rb = w * 32 + i * 16;
            size_t g = (size_t)(m0 + rb + srow) * K + k0 + sby;
            gl16(Ah + g, &sA[0][rb * 32]);
            gl16(Al + g, &sA[1][rb * 32]);
        }
        #pragma unroll
        for (int i = 0; i < BN / 64; i++) {     // B: BN/4 rows per wave
            int rb = w * (BN / 4) + i * 16;
            size_t g = (size_t)(n0 + rb + srow) * K + k0 + sby;
            gl16(Bh + g, &sB[0][rb * 32]);
            gl16(Bl + g, &sB[1][rb * 32]);
        }
        __syncthreads();

        s16x8 a_h[4], a_l[4];
        #pragma unroll
        for (int fm = 0; fm < 4; fm++) {
            int row = wm2 * 64 + fm * 16 + lr;
            int idx = row * 32 + lg * 8;
            a_h[fm] = *reinterpret_cast<const s16x8*>(&sA[0][idx]);
            a_l[fm] = *reinterpret_cast<const s16x8*>(&sA[1][idx]);
        }
        #pragma unroll
        for (int fn = 0; fn < NF; fn++) {
            int row = wn2 * WN + fn * 16 + lr;
            int idx = row * 32 + lg * 8;
            s16x8 b_h = *reinterpret_cast<const s16x8*>(&sB[0][idx]);
            s16x8 b_l = *reinterpret_cast<const s16x8*>(&sB[1][idx]);
            #pragma unroll
            for (int fm = 0; fm < 4; fm++) {
                acc[fm][fn] = __builtin_amdgcn_mfma_f32_16x16x32_bf16(a_h[fm], b_l, acc[fm][fn], 0, 0, 0);
                acc[fm][fn] = __builtin_amdgcn_mfma_f32_16x16x32_bf16(a_l[fm], b_h, acc[fm][fn], 0, 0, 0);
                acc[fm][fn] = __builtin_amdgcn_mfma_f32_16x16x32_bf16(a_h[fm], b_h, acc[fm][fn], 0, 0, 0);
            }
        }
        __syncthreads();
    }

    #pragma unroll
    for (int fm = 0; fm < 4; fm++) {
        #pragma unroll
        for (int fn = 0; fn < NF; fn++) {
            int col = n0 + wn2 * WN + fn * 16 + lr;
            #pragma unroll
            for (int r4 = 0; r4 < 4; r4++) {
                int row = m0 + wm2 * 64 + fm * 16 + lg * 4 + r4;
                float v = acc[fm][fn][r4];
                if (EPI == 0) {
                    Cf[(size_t)sk * (2048 * 512) + (size_t)row * N + col] = v;
                } else if (EPI == 1) {
                    v += bias0[col];
                    float u = v + 0.044715f * v * v * v;
                    float z2 = 1.5957691216057308f * u;
                    float ax = fabsf(z2);
                    float e = __expf(ax);
                    float th = 1.0f - 2.0f / (e + 1.0f);
                    th = (z2 < 0.0f) ? -th : th;
                    v = 0.5f * v * (1.0f + th);
                    u16 hh, ll; split2(v, hh, ll);
                    Xhi[(size_t)row * N + col] = hh;
                    Xlo[(size_t)row * N + col] = ll;
                } else {  // EPI 3: QKV
                    u16 hh, ll;
                    if (col < 512) {
                        v += bias0[col];
                        split2(v, hh, ll);
                        Xhi[(size_t)row * 512 + col] = hh;
                        Xlo[(size_t)row * 512 + col] = ll;
                    } else if (col < 1024) {
                        v += bias1[col - 512];
                        split2(v, hh, ll);
                        Yhi[(size_t)row * 512 + col - 512] = hh;
                        Ylo[(size_t)row * 512 + col - 512] = ll;
                    } else {
                        v += bias2[col - 1024];
                        split2(v, hh, ll);
                        int b = row >> 9, s = row & 511;
                        int hd = (col - 1024) >> 6, d = col & 63;
                        size_t o = ((size_t)((b * 8 + hd) * 64 + d)) * 512 + s;
                        Zhi[o] = hh;
                        Zlo[o] = ll;
                    }
                }
            }
        }
    }
}

// ---------------------------------------------------------------------------
// MFMA flash attention. Block = (b, head, 64-q tile); 4 waves x 16 q-rows.
// QK^T: bf16 triple (fp32-grade). Pass1 online (m,l); pass2 recompute,
// write exact-fp32 P to attn_out, P->bf16 via swizzled LDS, PV vs V^T (hi+lo).
// LDS rows 128B -> XOR swizzle byte^=((row&7)<<4) on both gl16-src and reads.
// ---------------------------------------------------------------------------
__global__ __launch_bounds__(256) void attn3(
        const u16* __restrict__ qh, const u16* __restrict__ ql,
        const u16* __restrict__ kh, const u16* __restrict__ kl,
        const u16* __restrict__ vth, const u16* __restrict__ vtl,
        const int* __restrict__ x,
        float* __restrict__ attn_out, u16* __restrict__ ctx_hi, u16* __restrict__ ctx_lo,
        int layer) {
    const int bid = blockIdx.x;
    const int qt = bid & 7;
    const int hh = (bid >> 3) & 7;
    const int b = bid >> 6;
    const int t = threadIdx.x;
    const int lane = t & 63, w = t >> 6;
    const int lr = lane & 15, lg = lane >> 4;

    __shared__ u16 sK[2][64 * 64];
    __shared__ u16 sV[2][64 * 64];
    __shared__ u16 sP[64 * 64];
    __shared__ float madd[SS];

    madd[t] = (x[b * SS + t] == 0) ? -1e9f : 0.0f;
    madd[t + 256] = (x[b * SS + t + 256] == 0) ? -1e9f : 0.0f;

    // Q fragments in registers (A-operand rows = q)
    s16x8 q_h[2], q_l[2];
    {
        const int qrow = qt * 64 + w * 16 + lr;
        size_t qb = ((size_t)(b * SS) + qrow) * 512 + hh * 64;
        #pragma unroll
        for (int c = 0; c < 2; c++) {
            q_h[c] = *reinterpret_cast<const s16x8*>(qh + qb + c * 32 + lg * 8);
            q_l[c] = *reinterpret_cast<const s16x8*>(ql + qb + c * 32 + lg * 8);
        }
    }
    __syncthreads();

    // staging lane geometry for 128B rows: 8 rows per 1KB issue
    const int kr8 = lane >> 3;                       // row within 8-row group
    const int kcs = ((lane & 7) * 8) ^ ((kr8 & 7) << 3);  // pre-swizzled u16 col

    const float scale = 0.125f;
    float mrow[4], lsum[4];
    #pragma unroll
    for (int r = 0; r < 4; r++) { mrow[r] = -1e30f; lsum[r] = 0.0f; }

    // ---------------- pass 1: online (m, l) ----------------
    for (int kt = 0; kt < 8; kt++) {
        #pragma unroll
        for (int i = 0; i < 2; i++) {
            int rb = w * 16 + i * 8;
            size_t g = ((size_t)(b * SS) + kt * 64 + rb + kr8) * 512 + hh * 64 + kcs;
            gl16(kh + g, &sK[0][rb * 64]);
            gl16(kl + g, &sK[1][rb * 64]);
        }
        __syncthreads();

        f32x4 s4[4] = {};
        #pragma unroll
        for (int c = 0; c < 2; c++) {
            #pragma unroll
            for (int f = 0; f < 4; f++) {
                int row = f * 16 + lr;
                int idx = row * 64 + (((c * 32 + lg * 8)) ^ ((row & 7) << 3));
                s16x8 k_h = *reinterpret_cast<const s16x8*>(&sK[0][idx]);
                s16x8 k_l = *reinterpret_cast<const s16x8*>(&sK[1][idx]);
                s4[f] = __builtin_amdgcn_mfma_f32_16x16x32_bf16(q_h[c], k_l, s4[f], 0, 0, 0);
                s4[f] = __builtin_amdgcn_mfma_f32_16x16x32_bf16(q_l[c], k_h, s4[f], 0, 0, 0);
                s4[f] = __builtin_amdgcn_mfma_f32_16x16x32_bf16(q_h[c], k_h, s4[f], 0, 0, 0);
            }
        }
        #pragma unroll
        for (int r = 0; r < 4; r++) {
            float sv[4], tmax = -1e30f;
            #pragma unroll
            for (int f = 0; f < 4; f++) {
                sv[f] = s4[f][r] * scale + madd[kt * 64 + f * 16 + lr];
                tmax = fmaxf(tmax, sv[f]);
            }
            #pragma unroll
            for (int off = 1; off < 16; off <<= 1) tmax = fmaxf(tmax, __shfl_xor(tmax, off));
            float nm = fmaxf(mrow[r], tmax);
            float ps = 0.0f;
            #pragma unroll
            for (int f = 0; f < 4; f++) ps += __expf(sv[f] - nm);
            #pragma unroll
            for (int off = 1; off < 16; off <<= 1) ps += __shfl_xor(ps, off);
            lsum[r] = lsum[r] * __expf(mrow[r] - nm) + ps;
            mrow[r] = nm;
        }
        __syncthreads();
    }

    float inv[4];
    #pragma unroll
    for (int r = 0; r < 4; r++) inv[r] = 1.0f / lsum[r];

    // ---------------- pass 2: P write + PV ----------------
    f32x4 cacc[4] = {};
    const size_t arow0 = ((size_t)((b * LN_LAYERS + layer) * HN + hh) * SS + qt * 64 + w * 16);

    for (int kt = 0; kt < 8; kt++) {
        #pragma unroll
        for (int i = 0; i < 2; i++) {
            int rb = w * 16 + i * 8;
            size_t gk = ((size_t)(b * SS) + kt * 64 + rb + kr8) * 512 + hh * 64 + kcs;
            size_t gv = ((size_t)((b * 8 + hh) * 64) + rb + kr8) * 512 + kt * 64 + kcs;
            gl16(kh + gk, &sK[0][rb * 64]);
            gl16(kl + gk, &sK[1][rb * 64]);
            gl16(vth + gv, &sV[0][rb * 64]);
            gl16(vtl + gv, &sV[1][rb * 64]);
        }
        __syncthreads();

        f32x4 s4[4] = {};
        #pragma unroll
        for (int c = 0; c < 2; c++) {
            #pragma unroll
            for (int f = 0; f < 4; f++) {
                int row = f * 16 + lr;
                int idx = row * 64 + (((c * 32 + lg * 8)) ^ ((row & 7) << 3));
                s16x8 k_h = *reinterpret_cast<const s16x8*>(&sK[0][idx]);
                s16x8 k_l = *reinterpret_cast<const s16x8*>(&sK[1][idx]);
                s4[f] = __builtin_amdgcn_mfma_f32_16x16x32_bf16(q_h[c], k_l, s4[f], 0, 0, 0);
                s4[f] = __builtin_amdgcn_mfma_f32_16x16x32_bf16(q_l[c], k_h, s4[f], 0, 0, 0);
                s4[f] = __builtin_amdgcn_mfma_f32_16x16x32_bf16(q_h[c], k_h, s4[f], 0, 0, 0);
            }
        }
        // P: exact fp32 to attn_out, bf16 to sP
        #pragma unroll
        for (int f = 0; f < 4; f++) {
            #pragma unroll
            for (int r = 0; r < 4; r++) {
                float p = __expf(s4[f][r] * scale + madd[kt * 64 + f * 16 + lr] - mrow[r]) * inv[r];
                attn_out[(arow0 + lg * 4 + r) * SS + kt * 64 + f * 16 + lr] = p;
                int qlcl = w * 16 + lg * 4 + r;
                sP[qlcl * 64 + ((f * 16 + lr) ^ ((qlcl & 7) << 3))] = bf16_rtne(p);
            }
        }
        // PV: A = P (rows = q), B = V^T (cols = d)
        #pragma unroll
        for (int c = 0; c < 2; c++) {
            int prow = w * 16 + lr;
            s16x8 pa = *reinterpret_cast<const s16x8*>(
                &sP[prow * 64 + ((c * 32 + lg * 8) ^ ((prow & 7) << 3))]);
            #pragma unroll
            for (int f = 0; f < 4; f++) {
                int vrow = f * 16 + lr;
                int idx = vrow * 64 + ((c * 32 + lg * 8) ^ ((vrow & 7) << 3));
                s16x8 v_h = *reinterpret_cast<const s16x8*>(&sV[0][idx]);
                s16x8 v_l = *reinterpret_cast<const s16x8*>(&sV[1][idx]);
                cacc[f] = __builtin_amdgcn_mfma_f32_16x16x32_bf16(pa, v_h, cacc[f], 0, 0, 0);
                cacc[f] = __builtin_amdgcn_mfma_f32_16x16x32_bf16(pa, v_l, cacc[f], 0, 0, 0);
            }
        }
        __syncthreads();
    }

    // ctx (bf16 hi/lo)
    #pragma unroll
    for (int f = 0; f < 4; f++) {
        #pragma unroll
        for (int r = 0; r < 4; r++) {
            u16 hh2, ll2;
            split2(cacc[f][r], hh2, ll2);
            size_t o = ((size_t)(b * SS) + qt * 64 + w * 16 + lg * 4 + r) * 512 + hh * 64 + f * 16 + lr;
            ctx_hi[o] = hh2;
            ctx_lo[o] = ll2;
        }
    }
}

// ---------------------------------------------------------------------------
// Fused split-K reduce + bias + residual + LayerNorm -> h fp32 + hi/lo
// ---------------------------------------------------------------------------
template <int NP>
__global__ void ln_fused(const float* __restrict__ parts, const float* __restrict__ bias,
                         const float* __restrict__ res, const float* __restrict__ g,
                         const float* __restrict__ bb, float* __restrict__ hout,
                         u16* __restrict__ ohi, u16* __restrict__ olo) {
    const int row = blockIdx.x;
    const int tid = threadIdx.x;
    const size_t base = (size_t)row * DM;

    float v0 = bias[tid] + res[base + tid];
    float v1 = bias[tid + 256] + res[base + tid + 256];
    #pragma unroll
    for (int p = 0; p < NP; p++) {
        v0 += parts[(size_t)p * (2048 * 512) + base + tid];
        v1 += parts[(size_t)p * (2048 * 512) + base + tid + 256];
    }

    __shared__ float red[4];
    float s = v0 + v1;
    #pragma unroll
    for (int off = 32; off; off >>= 1) s += __shfl_xor(s, off);
    if ((tid & 63) == 0) red[tid >> 6] = s;
    __syncthreads();
    float mean = (red[0] + red[1] + red[2] + red[3]) * (1.0f / 512.0f);

    float d0 = v0 - mean, d1 = v1 - mean;
    float t2 = d0 * d0 + d1 * d1;
    #pragma unroll
    for (int off = 32; off; off >>= 1) t2 += __shfl_xor(t2, off);
    __syncthreads();
    if ((tid & 63) == 0) red[tid >> 6] = t2;
    __syncthreads();
    float var = (red[0] + red[1] + red[2] + red[3]) * (1.0f / 512.0f);
    float rs = 1.0f / sqrtf(var + 1e-5f);

    float o0 = d0 * rs * g[tid] + bb[tid];
    float o1 = d1 * rs * g[tid + 256] + bb[tid + 256];
    hout[base + tid] = o0;
    hout[base + tid + 256] = o1;
    u16 hh, ll;
    split2(o0, hh, ll); ohi[base + tid] = hh;       olo[base + tid] = ll;
    split2(o1, hh, ll); ohi[base + tid + 256] = hh; olo[base + tid + 256] = ll;
}

// ---------------------------------------------------------------------------
extern "C" void kernel_launch(void* const* d_in, const int* in_sizes, int n_in,
                              void* d_out, int out_size, void* d_ws, size_t ws_size,
                              hipStream_t stream) {
    const int*   x    = (const int*)d_in[0];
    const float* emb  = (const float*)d_in[1];
    const float* pe   = (const float*)d_in[2];
    const float* WQ   = (const float*)d_in[3];
    const float* bQ   = (const float*)d_in[4];
    const float* WK   = (const float*)d_in[5];
    const float* bK   = (const float*)d_in[6];
    const float* WV   = (const float*)d_in[7];
    const float* bV   = (const float*)d_in[8];
    const float* WO   = (const float*)d_in[9];
    const float* bO   = (const float*)d_in[10];
    const float* ln1g = (const float*)d_in[11];
    const float* ln1b = (const float*)d_in[12];
    const float* W1   = (const float*)d_in[13];
    const float* b1   = (const float*)d_in[14];
    const float* W2   = (const float*)d_in[15];
    const float* b2   = (const float*)d_in[16];
    const float* ln2g = (const float*)d_in[17];
    const float* ln2b = (const float*)d_in[18];

    float* out = (float*)d_out;
    const size_t HS = (size_t)MROWS * DM;   // 1,048,576
    float* attn_base = out + HS;

    // workspace layout
    float* ws  = (float*)d_ws;
    float* h   = ws;                 // [2048,512] fp32
    float* pWO = h + HS;             // 2 partials
    float* pW2 = pWO + 2 * HS;       // 4 partials
    u16* u     = (u16*)(pW2 + 4 * HS);
    u16* h_hi   = u;            u16* h_lo   = h_hi + HS;
    u16* q_hi   = h_lo + HS;    u16* q_lo   = q_hi + HS;
    u16* k_hi   = q_lo + HS;    u16* k_lo   = k_hi + HS;
    u16* vt_hi  = k_lo + HS;    u16* vt_lo  = vt_hi + HS;
    u16* ctx_hi = vt_lo + HS;   u16* ctx_lo = ctx_hi + HS;
    u16* ff_hi  = ctx_lo + HS;  u16* ff_lo  = ff_hi + (size_t)MROWS * DFF;
    u16* w_hi   = ff_lo + (size_t)MROWS * DFF;
    u16* w_lo   = w_hi + (size_t)LN_LAYERS * 3145728;

    prep_kernel<<<LN_LAYERS * 768, 256, 0, stream>>>(WQ, WK, WV, WO, W1, W2, w_hi, w_lo);
    embed_kernel<<<(MROWS * DM) / 256, 256, 0, stream>>>(x, emb, pe, h, h_hi, h_lo);

    dim3 gQKV(1536 / 64, 16, 1);   // 24 x 16
    dim3 gWO(512 / 64, 16, 2);     // 8 x 16 x 2
    dim3 gW1(2048 / 128, 16, 1);   // 16 x 16
    dim3 gW2(512 / 64, 16, 4);     // 8 x 16 x 4

    for (int i = 0; i < LN_LAYERS; i++) {
        const u16* lwh = w_hi + (size_t)i * 3145728;
        const u16* lwl = w_lo + (size_t)i * 3145728;

        bgemm<64, 3><<<gQKV, 256, 0, stream>>>(h_hi, h_lo, lwh, lwl,
                bQ + i * DM, bK + i * DM, bV + i * DM,
                nullptr, q_hi, q_lo, k_hi, k_lo, vt_hi, vt_lo, 1536, DM, DM);

        attn3<<<BB * HN * (SS / 64), 256, 0, stream>>>(q_hi, q_lo, k_hi, k_lo,
                vt_hi, vt_lo, x, attn_base, ctx_hi, ctx_lo, i);

        bgemm<64, 0><<<gWO, 256, 0, stream>>>(ctx_hi, ctx_lo,
                lwh + 786432, lwl + 786432, nullptr, nullptr, nullptr,
                pWO, nullptr, nullptr, nullptr, nullptr, nullptr, nullptr, DM, DM, 256);
        ln_fused<2><<<MROWS, 256, 0, stream>>>(pWO, bO + i * DM, h,
                ln1g + i * DM, ln1b + i * DM, h, h_hi, h_lo);

        bgemm<128, 1><<<gW1, 256, 0, stream>>>(h_hi, h_lo,
                lwh + 1048576, lwl + 1048576, b1 + i * DFF, nullptr, nullptr,
                nullptr, ff_hi, ff_lo, nullptr, nullptr, nullptr, nullptr, DFF, DM, DM);

        bgemm<64, 0><<<gW2, 256, 0, stream>>>(ff_hi, ff_lo,
                lwh + 2097152, lwl + 2097152, nullptr, nullptr, nullptr,
                pW2, nullptr, nullptr, nullptr, nullptr, nullptr, nullptr, DM, DFF, 512);
        ln_fused<4><<<MROWS, 256, 0, stream>>>(pW2, b2 + i * DM, h,
                ln2g + i * DM, ln2b + i * DM, h, h_hi, h_lo);
    }

    hipMemcpyAsync(out, h, HS * sizeof(float), hipMemcpyDeviceToDevice, stream);
}